// Round 13
// baseline (931.323 us; speedup 1.0000x reference)
//
#include <hip/hip_runtime.h>

#define HW 1296
#define Nn 20736
#define N2 41472
#define TAPAD 72

typedef short bf16x8 __attribute__((ext_vector_type(8)));
typedef float f32x4 __attribute__((ext_vector_type(4)));

__device__ inline unsigned short f2b(float f){
  union { float f; unsigned u; } v; v.f = f;
  unsigned r = v.u + 0x7FFF + ((v.u >> 16) & 1);
  return (unsigned short)(r >> 16);
}
__device__ inline float b2f(unsigned short u){
  union { unsigned u; float f; } v; v.u = ((unsigned)u) << 16; return v.f;
}
__device__ inline float b2f_lo(unsigned u){
  union { unsigned u; float f; } v; v.u = u << 16; return v.f;
}
__device__ inline float b2f_hi(unsigned u){
  union { unsigned u; float f; } v; v.u = u & 0xffff0000u; return v.f;
}

__device__ __forceinline__ void pack_pairs(const float* a, unsigned* vals){
  #pragma unroll
  for (int i = 0; i < 32; ++i)
    vals[i] = (unsigned)f2b(a[2*i]) | ((unsigned)f2b(a[2*i+1]) << 16);
}

// LDS-transpose staged coalesced write (256 threads, each owns a 64-bf16 row)
__device__ __forceinline__ void staged_write(unsigned* lds, int tid, const unsigned* vals,
                                             uint4* o4, size_t R0, int rowu4, int cw,
                                             uint4* o4b){
  #pragma unroll
  for (int i = 0; i < 32; ++i) lds[tid*33 + i] = vals[i];
  __syncthreads();
  #pragma unroll
  for (int k = 0; k < 8; ++k){
    int j = k*256 + tid;
    int nn = j >> 3, w = j & 7;
    int base = nn*33 + w*4;
    uint4 v;
    v.x = lds[base]; v.y = lds[base+1]; v.z = lds[base+2]; v.w = lds[base+3];
    size_t oidx = (R0 + (size_t)nn)*(size_t)rowu4 + cw + w;
    o4[oidx] = v;
    if (o4b) o4b[oidx] = v;
  }
  __syncthreads();
}

// ---------------- utility ----------------

__global__ void k_zero(float* p, int n){
  int i = blockIdx.x*blockDim.x + threadIdx.x;
  if (i < n) p[i] = 0.f;
}

__device__ __forceinline__ void wpack_one(int e, const float* w, unsigned short* wp,
                                          int Cout, int Cin, int KT){
  int Kt32 = (Cin*KT) >> 5;
  int j    = e & 7;
  int lane = (e >> 3) & 63;
  int rest = e >> 9;
  int ks   = rest % Kt32;
  int mt   = rest / Kt32;
  int m  = mt*16 + (lane & 15);
  int k  = ks*32 + (lane >> 4)*8 + j;
  int dt = k / Cin, ci = k - dt*Cin;
  wp[e] = f2b(w[((size_t)m*Cin + ci)*KT + dt]);
}

__global__ void k_wprep(const float* w1, const float* w2, const float* wt,
                        const float* wc, const float* wte, const float* wce,
                        unsigned short* Wp1, unsigned short* Wp2, unsigned short* Wpt,
                        unsigned short* Wpc, unsigned short* Wpte, float* wTce){
  int idx = blockIdx.x*256 + threadIdx.x;
  if (idx < 49152){ wpack_one(idx, w1, Wp1, 64, 256, 3); return; }
  idx -= 49152;
  if (idx < 12288){ wpack_one(idx, w2, Wp2, 64, 64, 3); return; }
  idx -= 12288;
  if (idx < 12288){ wpack_one(idx, wt, Wpt, 64, 64, 3); return; }
  idx -= 12288;
  if (idx < 147456){ wpack_one(idx, wc, Wpc, 256, 192, 3); return; }
  idx -= 147456;
  if (idx < 4096){ wpack_one(idx, wte, Wpte, 64, 64, 1); return; }
  idx -= 4096;
  if (idx < 256){
    int o = idx / 64, i = idx % 64;
    wTce[i*4 + o] = wce[idx];
  }
}

// f32 [b][256][Nn] (x1 & x2) -> bf16 P-layout [b][plane][hw][256]; z<4: x1, z>=4: x2
__global__ void k_convT(const float* __restrict__ x1, const float* __restrict__ x2,
                        unsigned short* __restrict__ Pb){
  __shared__ unsigned lds[8448];
  int tid = threadIdx.x, z = blockIdx.z;
  int b = z & 3;
  const float* x = (z < 4) ? x1 : x2;
  int p0 = (z < 4) ? 0 : 16;
  int n0 = blockIdx.x*256, n = n0 + tid;
  const float* xb = x + (size_t)b*256*Nn + n;
  size_t R0 = (size_t)(b*32 + p0)*1296 + n0;
  uint4* o4 = (uint4*)Pb;
  for (int c0 = 0; c0 < 256; c0 += 64){
    float a[64];
    #pragma unroll
    for (int c = 0; c < 64; ++c) a[c] = xb[(size_t)(c0 + c)*Nn];
    unsigned vals[32];
    pack_pairs(a, vals);
    staged_write(lds, tid, vals, o4, R0, 32, c0 >> 3, nullptr);
  }
}

// ---------------- shared MFMA conv body (64-out-ch chunk) + fused BN-stats ----------------
__device__ __forceinline__ void mf_body(const unsigned short* __restrict__ P,
                                        const unsigned short* __restrict__ Wp,
                                        void* __restrict__ out, float* __restrict__ sums,
                                        float* sredf,
                                        int Cin, int Cout, int mz, int b,
                                        int Tout, int stride, int KT, int pad,
                                        int p0, int plo, int phi, int PT, int obf)
{
  int lane = threadIdx.x & 63;
  int wave = threadIdx.x >> 6;
  int tile = blockIdx.x*4 + wave;
  bool valid = (tile < 27);
  int t = blockIdx.y;
  int col = lane & 15, grp = lane >> 4;
  int Kt32 = (KT*Cin) >> 5;
  f32x4 acc[4][3];
  #pragma unroll
  for (int i = 0; i < 4; ++i)
    #pragma unroll
    for (int j = 0; j < 3; ++j) acc[i][j] = (f32x4){0.f, 0.f, 0.f, 0.f};
  if (valid){
    int hw0 = tile*48 + col;
    const unsigned short* wbase = Wp + ((size_t)(mz*4)*Kt32)*512 + lane*8;
    for (int dt = 0; dt < KT; ++dt){
      int p = t*stride + dt - pad + p0;
      if (p < plo || p >= phi) continue;
      const unsigned short* Pp = P + ((size_t)(b*PT + p)*1296 + hw0)*Cin + grp*8;
      int nCk = Cin >> 5;
      int ksg = (dt*Cin) >> 5;
      for (int kc = 0; kc < nCk; ++kc){
        bf16x8 bf0 = *(const bf16x8*)(Pp + (size_t)0*Cin  + kc*32);
        bf16x8 bf1 = *(const bf16x8*)(Pp + (size_t)16*Cin + kc*32);
        bf16x8 bf2 = *(const bf16x8*)(Pp + (size_t)32*Cin + kc*32);
        #pragma unroll
        for (int mf = 0; mf < 4; ++mf){
          bf16x8 af = *(const bf16x8*)(wbase + ((size_t)mf*Kt32 + ksg + kc)*512);
          acc[mf][0] = __builtin_amdgcn_mfma_f32_16x16x32_bf16(af, bf0, acc[mf][0], 0, 0, 0);
          acc[mf][1] = __builtin_amdgcn_mfma_f32_16x16x32_bf16(af, bf1, acc[mf][1], 0, 0, 0);
          acc[mf][2] = __builtin_amdgcn_mfma_f32_16x16x32_bf16(af, bf2, acc[mf][2], 0, 0, 0);
        }
      }
    }
    size_t cs = (size_t)Tout*1296;
    size_t obase = ((size_t)(b*Cout + mz*64 + grp*4))*cs + (size_t)t*1296;
    if (obf){
      unsigned short* o16 = (unsigned short*)out;
      #pragma unroll
      for (int mf = 0; mf < 4; ++mf)
        #pragma unroll
        for (int f = 0; f < 3; ++f){
          int hw = tile*48 + f*16 + col;
          #pragma unroll
          for (int r = 0; r < 4; ++r)
            o16[obase + (size_t)(mf*16 + r)*cs + hw] = f2b(acc[mf][f][r]);
        }
    } else {
      float* o32 = (float*)out;
      #pragma unroll
      for (int mf = 0; mf < 4; ++mf)
        #pragma unroll
        for (int f = 0; f < 3; ++f){
          int hw = tile*48 + f*16 + col;
          #pragma unroll
          for (int r = 0; r < 4; ++r)
            o32[obase + (size_t)(mf*16 + r)*cs + hw] = acc[mf][f][r];
        }
    }
  }
  float s[16], q[16];
  #pragma unroll
  for (int mf = 0; mf < 4; ++mf)
    #pragma unroll
    for (int r = 0; r < 4; ++r){
      float v0 = acc[mf][0][r], v1 = acc[mf][1][r], v2 = acc[mf][2][r];
      s[mf*4+r] = v0 + v1 + v2;
      q[mf*4+r] = v0*v0 + v1*v1 + v2*v2;
    }
  #pragma unroll
  for (int m = 1; m <= 8; m <<= 1){
    #pragma unroll
    for (int j = 0; j < 16; ++j){
      s[j] += __shfl_xor(s[j], m);
      q[j] += __shfl_xor(q[j], m);
    }
  }
  if (col == 0){
    #pragma unroll
    for (int j = 0; j < 16; ++j){
      sredf[((0*4 + wave)*4 + grp)*16 + j] = s[j];
      sredf[((1*4 + wave)*4 + grp)*16 + j] = q[j];
    }
  }
  __syncthreads();
  int tid = threadIdx.x;
  if (tid < 128){
    int stat = tid >> 6, ch = tid & 63;
    int rr = ch & 3, gg = (ch >> 2) & 3, mm = ch >> 4;
    int j = mm*4 + rr;
    float v = sredf[((stat*4 + 0)*4 + gg)*16 + j] + sredf[((stat*4 + 1)*4 + gg)*16 + j]
            + sredf[((stat*4 + 2)*4 + gg)*16 + j] + sredf[((stat*4 + 3)*4 + gg)*16 + j];
    atomicAdd(&sums[stat*Cout + mz*64 + ch], v);
  }
}

// generic (te / tam / Mb convs)
__launch_bounds__(256)
__global__ void k_mfconv(const unsigned short* __restrict__ P, const unsigned short* __restrict__ Wp,
                         float* __restrict__ out, int Cin, int Cout, int Mz,
                         int Tout, int stride, int KT, int pad, int p0, int plo, int phi, int PT,
                         float* __restrict__ sums, int obf)
{
  __shared__ float sred[2*4*4*16];
  int bz = blockIdx.z; int b = bz / Mz; int mz = bz - b*Mz;
  mf_body(P, Wp, out, sums, sred, Cin, Cout, mz, b, Tout, stride, KT, pad,
          p0, plo, phi, PT, obf);
}

// conv1 A & B merged (z in [0,8): which = z>>2, b = z&3)
__launch_bounds__(256)
__global__ void k_mfconv_ab(const unsigned short* __restrict__ P, const unsigned short* __restrict__ Wp,
                            float* __restrict__ A, float* __restrict__ Bb,
                            float* __restrict__ stats)
{
  __shared__ float sred[2*4*4*16];
  int bz = blockIdx.z; int which = bz >> 2; int b = bz & 3;
  float* out = which ? Bb : A;
  float* sums = stats + (size_t)which*512;
  int p0 = which*16;
  mf_body(P, Wp, out, sums, sred, 256, 64, 0, b, 16, 1, 3, 1, p0, p0, p0+16, 32, 0);
}

// conv2 over PG4 (16 pseudo-batches = stage*4+b), bf16 out
__launch_bounds__(256)
__global__ void k_mfconv4(const unsigned short* __restrict__ PG4, const unsigned short* __restrict__ Wp,
                          unsigned short* __restrict__ Rout, float* __restrict__ stats)
{
  __shared__ float sred[2*4*4*16];
  int pb = blockIdx.z;
  int stage = pb >> 2;
  int slot = (stage < 2) ? (13 + stage) : (15 + stage);
  mf_body(PG4, Wp, Rout, stats + (size_t)slot*512, sred, 64, 64, 0, pb,
          16, 1, 3, 1, 0, 0, 16, 16, 1);
}

// cat convs: block = (tile, t, which*4+b); wave w = output chunk mz=w.
// All 4 waves read identical B-fragments -> L1 reuse (no 4x HBM refetch).
__launch_bounds__(256)
__global__ void k_mfconvcat2(const unsigned short* __restrict__ PCAT1,
                             const unsigned short* __restrict__ PCAT2,
                             const unsigned short* __restrict__ Wp,
                             unsigned short* __restrict__ CATR1,
                             unsigned short* __restrict__ CATR2,
                             float* __restrict__ stats)
{
  const int Cin = 192, Cout = 256, Tout = 16, PT = 16;
  int z = blockIdx.z;
  int which = z >> 2, b = z & 3;
  const unsigned short* P = which ? PCAT2 : PCAT1;
  unsigned short* out = which ? CATR2 : CATR1;
  float* sums = stats + (size_t)(19 + which)*512;
  int lane = threadIdx.x & 63;
  int mz = threadIdx.x >> 6;           // wave owns one 64-channel chunk
  int tile = blockIdx.x;               // 0..26
  int t = blockIdx.y;
  int col = lane & 15, grp = lane >> 4;
  const int Kt32 = (3*Cin) >> 5;       // 18
  f32x4 acc[4][3];
  #pragma unroll
  for (int i = 0; i < 4; ++i)
    #pragma unroll
    for (int j = 0; j < 3; ++j) acc[i][j] = (f32x4){0.f, 0.f, 0.f, 0.f};
  int hw0 = tile*48 + col;
  const unsigned short* wbase = Wp + ((size_t)(mz*4)*Kt32)*512 + lane*8;
  for (int dt = 0; dt < 3; ++dt){
    int p = t + dt - 1;
    if (p < 0 || p >= 16) continue;
    const unsigned short* Pp = P + ((size_t)(b*PT + p)*1296 + hw0)*Cin + grp*8;
    int ksg = (dt*Cin) >> 5;
    for (int kc = 0; kc < 6; ++kc){
      bf16x8 bf0 = *(const bf16x8*)(Pp + (size_t)0*Cin  + kc*32);
      bf16x8 bf1 = *(const bf16x8*)(Pp + (size_t)16*Cin + kc*32);
      bf16x8 bf2 = *(const bf16x8*)(Pp + (size_t)32*Cin + kc*32);
      #pragma unroll
      for (int mf = 0; mf < 4; ++mf){
        bf16x8 af = *(const bf16x8*)(wbase + ((size_t)mf*Kt32 + ksg + kc)*512);
        acc[mf][0] = __builtin_amdgcn_mfma_f32_16x16x32_bf16(af, bf0, acc[mf][0], 0, 0, 0);
        acc[mf][1] = __builtin_amdgcn_mfma_f32_16x16x32_bf16(af, bf1, acc[mf][1], 0, 0, 0);
        acc[mf][2] = __builtin_amdgcn_mfma_f32_16x16x32_bf16(af, bf2, acc[mf][2], 0, 0, 0);
      }
    }
  }
  size_t cs = (size_t)Tout*1296;
  size_t obase = ((size_t)(b*Cout + mz*64 + grp*4))*cs + (size_t)t*1296;
  #pragma unroll
  for (int mf = 0; mf < 4; ++mf)
    #pragma unroll
    for (int f = 0; f < 3; ++f){
      int hw = tile*48 + f*16 + col;
      #pragma unroll
      for (int r = 0; r < 4; ++r)
        out[obase + (size_t)(mf*16 + r)*cs + hw] = f2b(acc[mf][f][r]);
    }
  // per-wave stats (waves own different chunks -> direct atomics from col==0 lanes)
  float s[16], q[16];
  #pragma unroll
  for (int mf = 0; mf < 4; ++mf)
    #pragma unroll
    for (int r = 0; r < 4; ++r){
      float v0 = acc[mf][0][r], v1 = acc[mf][1][r], v2 = acc[mf][2][r];
      s[mf*4+r] = v0 + v1 + v2;
      q[mf*4+r] = v0*v0 + v1*v1 + v2*v2;
    }
  #pragma unroll
  for (int m = 1; m <= 8; m <<= 1){
    #pragma unroll
    for (int j = 0; j < 16; ++j){
      s[j] += __shfl_xor(s[j], m);
      q[j] += __shfl_xor(q[j], m);
    }
  }
  if (col == 0){
    #pragma unroll
    for (int j = 0; j < 16; ++j){
      int mf = j >> 2, r = j & 3;
      int ch = mz*64 + mf*16 + grp*4 + r;
      atomicAdd(&sums[ch], s[j]);
      atomicAdd(&sums[256 + ch], q[j]);
    }
  }
}

// ---------------- ce pointwise conv 64->4 merged (z in [0,8)) ----------------
__global__ void k_tconvm(const float* __restrict__ A, const float* __restrict__ Bb,
                         const float* __restrict__ wT,
                         float* __restrict__ yc2, float* __restrict__ stats)
{
  __shared__ float r1[4][64], r2[4][64];
  int z = blockIdx.z;
  int which = z >> 2, b = z & 3;
  const float* xA = which ? Bb : A;
  float* out = yc2 + (size_t)which*331776;
  float* sums = stats + (size_t)(15 + which)*512;
  int o  = threadIdx.x;  // 4
  int ty = threadIdx.y;  // 64
  int t  = blockIdx.y;
  int hw4 = blockIdx.x*64 + ty;
  bool valid = (hw4 < 324);
  float4 acc = make_float4(0.f,0.f,0.f,0.f);
  if (valid){
    const float4* xr = (const float4*)xA + ((size_t)b*64*16 + t)*324 + hw4;
    const float* wp  = wT + o;
    size_t xstep = (size_t)16*324;
    for (int i = 0; i < 64; ++i){
      float4 xv = *xr;
      float  wv = *wp;
      acc.x = fmaf(wv, xv.x, acc.x);
      acc.y = fmaf(wv, xv.y, acc.y);
      acc.z = fmaf(wv, xv.z, acc.z);
      acc.w = fmaf(wv, xv.w, acc.w);
      xr += xstep; wp += 4;
    }
    float4* op = (float4*)out + ((size_t)(b*4 + o)*16 + t)*324 + hw4;
    *op = acc;
  }
  r1[o][ty] = acc.x + acc.y + acc.z + acc.w;
  r2[o][ty] = acc.x*acc.x + acc.y*acc.y + acc.z*acc.z + acc.w*acc.w;
  __syncthreads();
  int tid = threadIdx.y*4 + threadIdx.x;
  for (int k = 32; k > 0; k >>= 1){
    if (ty < k){
      r1[o][ty] += r1[o][ty+k];
      r2[o][ty] += r2[o][ty+k];
    }
    __syncthreads();
  }
  if (tid < 4) atomicAdd(&sums[tid],     r1[tid][0]);
  else if (tid < 8) atomicAdd(&sums[tid], r2[tid-4][0]);
}

// ---------------- BN ----------------

__global__ void k_planestats(const float* __restrict__ A, const float* __restrict__ B,
                             float* __restrict__ s22, float* __restrict__ s23){
  int which = blockIdx.z, c = blockIdx.y, tid = threadIdx.x;
  const float* src = which ? B : A;
  int toff = which ? 0 : 15;
  float* dst = which ? s23 : s22;
  float s = 0.f, q = 0.f;
  for (int idx = tid; idx < 4*1296; idx += 256){
    int b = idx / 1296, hw = idx - b*1296;
    float v = src[(((size_t)b*64 + c)*16 + toff)*1296 + hw];
    s += v; q += v*v;
  }
  __shared__ float r1[256], r2[256];
  r1[tid] = s; r2[tid] = q; __syncthreads();
  for (int k = 128; k > 0; k >>= 1){
    if (tid < k){ r1[tid] += r1[tid+k]; r2[tid] += r2[tid+k]; }
    __syncthreads();
  }
  if (tid == 0){ dst[c] = r1[0]; dst[64 + c] = r2[0]; }
}

__global__ void k_combine(float* stats){
  int i = threadIdx.x;
  if (i < 128)
    stats[2*512 + i] = stats[0*512 + i] + stats[1*512 + i]
                     - stats[22*512 + i] - stats[23*512 + i] + stats[21*512 + i];
}

// BN+ReLU from bf16 raw cat outputs -> f32 d_out halves; z: b + 4*which
__global__ void k_bnrelu_out(const unsigned short* __restrict__ x1bf,
                             const unsigned short* __restrict__ x2bf,
                             const float* __restrict__ stats19,
                             const float* __restrict__ g,
                             const float* __restrict__ bet, float invc,
                             float* __restrict__ out)
{
  int z = blockIdx.z;
  int b = z & 3, which = z >> 2;
  const unsigned short* xbf = which ? x2bf : x1bf;
  const float* sums = stats19 + (size_t)which*512;
  float* op = out + (size_t)which*4*256*Nn;
  int c = blockIdx.y;
  int n8 = blockIdx.x*256 + threadIdx.x;
  if (n8 >= 2592) return;
  float m  = sums[c]*invc;
  float v  = fmaxf(sums[256+c]*invc - m*m, 0.f);
  float sc = g[c]*rsqrtf(v + 1e-5f);
  float bb = bet[c] - m*sc;
  size_t base = ((size_t)(b*256 + c))*Nn + (size_t)n8*8;
  uint4 u = *(const uint4*)(xbf + base);
  float4 o0, o1;
  o0.x = fmaxf(fmaf(b2f_lo(u.x), sc, bb), 0.f);
  o0.y = fmaxf(fmaf(b2f_hi(u.x), sc, bb), 0.f);
  o0.z = fmaxf(fmaf(b2f_lo(u.y), sc, bb), 0.f);
  o0.w = fmaxf(fmaf(b2f_hi(u.y), sc, bb), 0.f);
  o1.x = fmaxf(fmaf(b2f_lo(u.z), sc, bb), 0.f);
  o1.y = fmaxf(fmaf(b2f_hi(u.z), sc, bb), 0.f);
  o1.z = fmaxf(fmaf(b2f_lo(u.w), sc, bb), 0.f);
  o1.w = fmaxf(fmaf(b2f_hi(u.w), sc, bb), 0.f);
  *(float4*)(op + base) = o0;
  *(float4*)(op + base + 4) = o1;
}

// merged BN+ReLU in place on A & Bb + p6 accumulation (z in [0,8))
__global__ void k_bnrelu_mean2(float* __restrict__ A, float* __restrict__ Bb,
                               const float* __restrict__ stats,
                               const float* __restrict__ g, const float* __restrict__ bet,
                               float invc, float* __restrict__ p6a, float* __restrict__ p6b)
{
  __shared__ float p6loc[36];
  int z = blockIdx.z;
  int which = z >> 2, b = z & 3;
  float* x = which ? Bb : A;
  const float* sums = stats + (size_t)which*512;
  float* p6 = which ? p6b : p6a;
  int tid = threadIdx.x;
  if (tid < 36) p6loc[tid] = 0.f;
  __syncthreads();
  int hw = blockIdx.x*256 + tid;
  int c = blockIdx.y;
  if (hw < 1296){
    float m  = sums[c]*invc;
    float v  = fmaxf(sums[64+c]*invc - m*m, 0.f);
    float sc = g[c]*rsqrtf(v + 1e-5f);
    float bb = bet[c] - m*sc;
    float* xb = x + ((size_t)(b*64 + c)*16)*1296 + hw;
    float s = 0.f;
    #pragma unroll
    for (int t = 0; t < 16; ++t){
      float val = fmaxf(fmaf(xb[(size_t)t*1296], sc, bb), 0.f);
      xb[(size_t)t*1296] = val;
      s += val;
    }
    int h = hw / 36, w = hw - h*36;
    atomicAdd(&p6loc[(h/6)*6 + (w/6)], s*(1.f/16.f));
  }
  __syncthreads();
  if (tid < 36) atomicAdd(&p6[((size_t)(b*64 + c))*36 + tid], p6loc[tid]);
}

// BN+ReLU on raw [b][64][L] (f32 or bf16 per xbf) -> bf16 P rows [b][n][outC] at coff
__global__ void k_bnT(const void* __restrict__ xraw, const float* __restrict__ sums,
                      const float* __restrict__ g, const float* __restrict__ bet, float invc,
                      unsigned short* __restrict__ P1, unsigned short* __restrict__ P2,
                      int L, int outC, int coff, int xbf)
{
  __shared__ unsigned lds[8448];
  int tid = threadIdx.x, b = blockIdx.z;
  int n0 = blockIdx.x*256, n = n0 + tid;
  float a[64];
  if (xbf){
    const unsigned short* xb = (const unsigned short*)xraw + (size_t)b*64*L + n;
    #pragma unroll
    for (int c = 0; c < 64; ++c){
      float m  = sums[c]*invc;
      float vv = fmaxf(sums[64+c]*invc - m*m, 0.f);
      float sc = g[c]*rsqrtf(vv + 1e-5f);
      float bb = bet[c] - m*sc;
      a[c] = fmaxf(fmaf(b2f(xb[(size_t)c*L]), sc, bb), 0.f);
    }
  } else {
    const float* xb = (const float*)xraw + (size_t)b*64*L + n;
    #pragma unroll
    for (int c = 0; c < 64; ++c){
      float m  = sums[c]*invc;
      float vv = fmaxf(sums[64+c]*invc - m*m, 0.f);
      float sc = g[c]*rsqrtf(vv + 1e-5f);
      float bb = bet[c] - m*sc;
      a[c] = fmaxf(fmaf(xb[(size_t)c*L], sc, bb), 0.f);
    }
  }
  unsigned vals[32];
  pack_pairs(a, vals);
  staged_write(lds, tid, vals, (uint4*)P1, (size_t)b*L + n0, outC >> 3, coff >> 3,
               P2 ? (uint4*)P2 : nullptr);
}

// merged conv2 BN -> concat buffers (z in [0,16): stage = z>>2, b = z&3)
__global__ void k_bnT4(const unsigned short* __restrict__ R4, const float* __restrict__ stats,
                       const float* __restrict__ g, const float* __restrict__ bet, float invc,
                       unsigned short* __restrict__ PCAT1, unsigned short* __restrict__ PCAT2)
{
  __shared__ unsigned lds[8448];
  int z = blockIdx.z;
  int stage = z >> 2, b = z & 3;
  int slot = (stage < 2) ? (13 + stage) : (15 + stage);
  const float* sums = stats + (size_t)slot*512;
  unsigned short* P1 = (stage == 0 || stage == 3) ? PCAT1 : PCAT2;
  int cw = (stage < 2) ? 0 : 8;
  int tid = threadIdx.x;
  int n0 = blockIdx.x*256, n = n0 + tid;
  const unsigned short* xb = R4 + (size_t)z*64*Nn + n;
  float a[64];
  #pragma unroll
  for (int c = 0; c < 64; ++c){
    float m  = sums[c]*invc;
    float vv = fmaxf(sums[64+c]*invc - m*m, 0.f);
    float sc = g[c]*rsqrtf(vv + 1e-5f);
    float bb = bet[c] - m*sc;
    a[c] = fmaxf(fmaf(b2f(xb[(size_t)c*Nn]), sc, bb), 0.f);
  }
  unsigned vals[32];
  pack_pairs(a, vals);
  staged_write(lds, tid, vals, (uint4*)P1, (size_t)b*Nn + n0, 24, cw, nullptr);
}

// composed-concat BN+ReLU -> bf16 PTE [b][n][64]
__global__ void k_bnT_cc(const float* __restrict__ A, const float* __restrict__ M,
                         const float* __restrict__ B, const float* __restrict__ sums,
                         const float* __restrict__ g, const float* __restrict__ bet,
                         float invc, unsigned short* __restrict__ P1)
{
  __shared__ unsigned lds[8448];
  int tid = threadIdx.x, b = blockIdx.z;
  int n0 = blockIdx.x*256, n = n0 + tid;
  int t = n / 1296, hw = n - t*1296;
  const float* src; size_t cstride;
  if (t < 15){ src = A + ((size_t)(b*64)*16 + t)*1296 + hw; cstride = (size_t)16*1296; }
  else if (t < 17){ src = M + ((size_t)(b*64)*2 + (t-15))*1296 + hw; cstride = (size_t)2*1296; }
  else { src = B + ((size_t)(b*64)*16 + (t-16))*1296 + hw; cstride = (size_t)16*1296; }
  float a[64];
  #pragma unroll
  for (int c = 0; c < 64; ++c){
    float m  = sums[c]*invc;
    float vv = fmaxf(sums[64+c]*invc - m*m, 0.f);
    float sc = g[c]*rsqrtf(vv + 1e-5f);
    float bb = bet[c] - m*sc;
    a[c] = fmaxf(fmaf(src[c*cstride], sc, bb), 0.f);
  }
  unsigned vals[32];
  pack_pairs(a, vals);
  staged_write(lds, tid, vals, (uint4*)P1, (size_t)b*N2 + n0, 8, 0, nullptr);
}

// ---------------- PAM (merged, z in [0,8): which = z>>2, b = z&3) ----------------

__global__ void k_pamenc1m(const float* __restrict__ p6a, const float* __restrict__ p6b,
                           const float* __restrict__ pe_w,
                           float* __restrict__ pf2, float* __restrict__ stats){
  __shared__ float psh[64];
  int z = blockIdx.z;
  int which = z >> 2, b = z & 3;
  const float* p6 = which ? p6b : p6a;
  float* sl = stats + (size_t)(which ? 9 : 5)*512;
  float* pf = pf2 + (size_t)which*12800;
  int cell = blockIdx.x;
  int o = threadIdx.x;
  int s, off;
  if (cell < 1){ s=1; off=0; } else if (cell < 5){ s=2; off=1; }
  else if (cell < 14){ s=3; off=5; } else { s=6; off=14; }
  int local = cell - off, ph = local/s, pw = local%s;
  int bs = 6/s;
  const float* pp = p6 + ((size_t)(b*64 + o))*36;
  float sum = 0.f;
  for (int i = 0; i < bs; ++i)
    for (int j = 0; j < bs; ++j)
      sum += pp[(ph*bs + i)*6 + (pw*bs + j)];
  psh[o] = sum * ((float)(s*s) * (1.f/1296.f));
  __syncthreads();
  int grp = (cell < 1) ? 0 : (cell < 5) ? 1 : (cell < 14) ? 2 : 3;
  const float* w = pe_w + (size_t)grp*4096 + o*64;
  float acc = 0.f;
  #pragma unroll
  for (int i = 0; i < 64; ++i) acc = fmaf(w[i], psh[i], acc);
  pf[((size_t)b*64 + o)*50 + cell] = acc;
  atomicAdd(&sl[grp*128 + o], acc);
  atomicAdd(&sl[grp*128 + 64 + o], acc*acc);
}

__launch_bounds__(128)
__global__ void k_pamenc2m(const float* __restrict__ pf2, float* __restrict__ stats,
                           const float* __restrict__ pe_g, const float* __restrict__ pe_b,
                           const float* __restrict__ wk, const float* __restrict__ bk,
                           const float* __restrict__ wv, const float* __restrict__ bv,
                           const float* __restrict__ wq, const float* __restrict__ bq,
                           float* __restrict__ vb2, float* __restrict__ KW2,
                           float* __restrict__ sb2)
{
  __shared__ float yk[64];
  __shared__ float kbl[16];
  int z = blockIdx.z;
  int which = z >> 2, b = z & 3;
  const float* pf = pf2 + (size_t)which*12800;
  const float* sl = stats + (size_t)(which ? 9 : 5)*512;
  float* vb = vb2 + (size_t)which*12800;
  float* KW = KW2 + (size_t)which*12800;
  float* sb = sb2 + (size_t)which*256;
  int k = blockIdx.x;
  int tid = threadIdx.x;
  int grp = (k < 1) ? 0 : (k < 5) ? 1 : (k < 14) ? 2 : 3;
  const float ss2[4] = {1.f, 4.f, 9.f, 36.f};
  if (tid < 64){
    float invc = 1.f/(4.f*ss2[grp]);
    float m = sl[grp*128 + tid]*invc;
    float var = fmaxf(sl[grp*128 + 64 + tid]*invc - m*m, 0.f);
    float sc = pe_g[grp*64 + tid]*rsqrtf(var + 1e-5f);
    float sh = pe_b[grp*64 + tid] - m*sc;
    yk[tid] = fmaxf(fmaf(pf[((size_t)b*64 + tid)*50 + k], sc, sh), 0.f);
  }
  __syncthreads();
  if (tid < 16){
    float s = bk[tid];
    #pragma unroll
    for (int c = 0; c < 64; ++c) s = fmaf(wk[tid*64 + c], yk[c], s);
    kbl[tid] = s;
  } else if (tid < 80){
    int c = tid - 16;
    float s = bv[c];
    #pragma unroll
    for (int i = 0; i < 64; ++i) s = fmaf(wv[c*64 + i], yk[i], s);
    vb[((size_t)b*50 + k)*64 + c] = s;
  }
  __syncthreads();
  if (tid < 64){
    float s = 0.f;
    #pragma unroll
    for (int o = 0; o < 16; ++o) s = fmaf(kbl[o], wq[o*64 + tid], s);
    KW[((size_t)b*50 + k)*64 + tid] = s;
  } else if (tid == 64){
    float s = 0.f;
    #pragma unroll
    for (int o = 0; o < 16; ++o) s = fmaf(kbl[o], bq[o], s);
    sb[(size_t)b*50 + k] = s;
  }
}

// merged pamattn: z in [0,8): which = z>>2, b = z&3; out -> PG4 stage `which`
__launch_bounds__(256, 1)
__global__ void k_pamattnm(const float* __restrict__ A, const float* __restrict__ Bb,
                           const float* __restrict__ KW2, const float* __restrict__ sb2,
                           const float* __restrict__ vb2, const float* __restrict__ scp,
                           unsigned short* __restrict__ PG4)
{
  __shared__ unsigned smem_u[8448];
  float* smem = (float*)smem_u;
  int z = blockIdx.z;
  int which = z >> 2, b = z & 3;
  const float* x = which ? Bb : A;
  const float* KW = KW2 + (size_t)which*12800;
  const float* sbb = sb2 + (size_t)which*256;
  const float* vbuf = vb2 + (size_t)which*12800;
  int tid = threadIdx.x;
  for (int i = tid; i < 3200; i += 256){
    smem[i]        = KW[(size_t)b*3200 + i];
    smem[3200 + i] = vbuf[(size_t)b*3200 + i];
  }
  if (tid < 50) smem[6400 + tid] = sbb[(size_t)b*50 + tid];
  __syncthreads();
  int n0 = blockIdx.x*256;
  int n = n0 + tid;
  const float* xb = x + (size_t)b*64*Nn + n;
  float xv[64];
  #pragma unroll
  for (int c = 0; c < 64; ++c) xv[c] = xb[(size_t)c*Nn];
  float s[50];
  const float4* kw4 = (const float4*)smem;
  #pragma unroll
  for (int k = 0; k < 50; ++k){
    float t = smem[6400 + k];
    #pragma unroll
    for (int c4 = 0; c4 < 16; ++c4){
      float4 kw = kw4[k*16 + c4];
      t = fmaf(xv[c4*4+0], kw.x, t);
      t = fmaf(xv[c4*4+1], kw.y, t);
      t = fmaf(xv[c4*4+2], kw.z, t);
      t = fmaf(xv[c4*4+3], kw.w, t);
    }
    s[k] = t;
  }
  float mx = -1e30f;
  #pragma unroll
  for (int k = 0; k < 50; ++k) mx = fmaxf(mx, s[k]);
  float sum = 0.f;
  #pragma unroll
  for (int k = 0; k < 50; ++k){ float p = __expf(s[k]-mx); s[k] = p; sum += p; }
  float sc = scp[0]/sum;
  const float4* vl4 = (const float4*)(smem + 3200);
  #pragma unroll
  for (int k = 0; k < 50; ++k){
    float pk = sc * s[k];
    #pragma unroll
    for (int c4 = 0; c4 < 16; ++c4){
      float4 v = vl4[k*16 + c4];
      xv[c4*4+0] = fmaf(pk, v.x, xv[c4*4+0]);
      xv[c4*4+1] = fmaf(pk, v.y, xv[c4*4+1]);
      xv[c4*4+2] = fmaf(pk, v.z, xv[c4*4+2]);
      xv[c4*4+3] = fmaf(pk, v.w, xv[c4*4+3]);
    }
  }
  __syncthreads();
  unsigned vals[32];
  pack_pairs(xv, vals);
  staged_write(smem_u, tid, vals, (uint4*)PG4, (size_t)(which*4 + b)*Nn + n0, 8, 0, nullptr);
}

// ---------------- CAM (merged) ----------------

__global__ void k_camenergy2m(const float* __restrict__ A, const float* __restrict__ Bb,
                              const float* __restrict__ yc2, const float* __restrict__ stats,
                              const float* __restrict__ ce_g, const float* __restrict__ ce_b,
                              float invc, float* __restrict__ e_cam){
  __shared__ float yl[4][256];
  int z = blockIdx.z;
  int which = z >> 2, b = z & 3;
  const float* x = which ? Bb : A;
  const float* yc = yc2 + (size_t)which*331776;
  const float* sums = stats + (size_t)(15 + which)*512;
  float* e = e_cam + (size_t)which*1024;
  int tid = threadIdx.x;
  int n0 = blockIdx.x*256;
  #pragma unroll
  for (int k = 0; k < 4; ++k){
    float m  = sums[k]*invc;
    float vv = fmaxf(sums[4+k]*invc - m*m, 0.f);
    float sck = ce_g[k]*rsqrtf(vv + 1e-5f);
    float bbk = ce_b[k] - m*sck;
    float raw = yc[((size_t)b*4+k)*Nn + n0 + tid];
    yl[k][tid] = fmaxf(fmaf(raw, sck, bbk), 0.f);
  }
  __syncthreads();
  int c = tid & 63, ks = tid >> 6;
  const float* xr = x + (size_t)(b*64+c)*Nn + n0;
  const float* yr = yl[ks];
  float acc = 0.f;
  #pragma unroll 8
  for (int i = 0; i < 256; ++i) acc = fmaf(xr[i], yr[i], acc);
  atomicAdd(&e[((size_t)(b*64)+c)*4 + ks], acc);
}

// merged camapply: out -> PG4 stage 2+which
__global__ void k_camapplyTm(const float* __restrict__ A, const float* __restrict__ Bb,
                             const float* __restrict__ yc2, const float* __restrict__ stats,
                             const float* __restrict__ ce_g, const float* __restrict__ ce_b,
                             float invc, const float* __restrict__ e_cam,
                             const float* __restrict__ scp, unsigned short* __restrict__ PG4){
  __shared__ float pw[64][4];
  __shared__ unsigned lds[8448];
  int z = blockIdx.z;
  int which = z >> 2, b = z & 3;
  const float* x = which ? Bb : A;
  const float* yc = yc2 + (size_t)which*331776;
  const float* sums = stats + (size_t)(15 + which)*512;
  const float* e = e_cam + (size_t)which*1024;
  int tid = threadIdx.x;
  if (tid < 64){
    const float* er = e + (size_t)(b*64+tid)*4;
    float e0=er[0], e1=er[1], e2=er[2], e3=er[3];
    float mx = fmaxf(fmaxf(e0,e1), fmaxf(e2,e3));
    float z0=mx-e0, z1=mx-e1, z2=mx-e2, z3=mx-e3;
    float zm = fmaxf(fmaxf(z0,z1), fmaxf(z2,z3));
    float p0=__expf(z0-zm), p1=__expf(z1-zm), p2=__expf(z2-zm), p3=__expf(z3-zm);
    float inv = 1.f/(p0+p1+p2+p3);
    pw[tid][0]=p0*inv; pw[tid][1]=p1*inv; pw[tid][2]=p2*inv; pw[tid][3]=p3*inv;
  }
  __syncthreads();
  int n0 = blockIdx.x*256;
  int n = n0 + tid;
  float yv[4];
  #pragma unroll
  for (int k = 0; k < 4; ++k){
    float m  = sums[k]*invc;
    float vv = fmaxf(sums[4+k]*invc - m*m, 0.f);
    float sck = ce_g[k]*rsqrtf(vv + 1e-5f);
    float bbk = ce_b[k] - m*sck;
    yv[k] = fmaxf(fmaf(yc[((size_t)b*4+k)*Nn + n], sck, bbk), 0.f);
  }
  float sc = scp[0];
  const float* xb = x + (size_t)b*64*Nn + n;
  float a[64];
  #pragma unroll
  for (int c = 0; c < 64; ++c){
    a[c] = fmaf(sc, pw[c][0]*yv[0] + pw[c][1]*yv[1] + pw[c][2]*yv[2] + pw[c][3]*yv[3],
                xb[(size_t)c*Nn]);
  }
  unsigned vals[32];
  pack_pairs(a, vals);
  staged_write(lds, tid, vals, (uint4*)PG4, (size_t)((2+which)*4 + b)*Nn + n0, 8, 0, nullptr);
}

// ---------------- TAM ----------------

__launch_bounds__(256)
__global__ void k_tamenergy_mf(const unsigned short* __restrict__ X,
                               const unsigned short* __restrict__ Y,
                               float* __restrict__ E){
  int b = blockIdx.z;
  int wave = threadIdx.x >> 6, lane = threadIdx.x & 63;
  int r = lane & 15, g = lane >> 4;
  const unsigned short* Xb = X + (size_t)b*32*82944;
  const unsigned short* Yb = Y + (size_t)b*32*82944;
  f32x4 a00 = (f32x4){0.f,0.f,0.f,0.f};
  f32x4 a01 = a00, a10 = a00, a11 = a00;
  int c0 = (blockIdx.x*4 + wave)*8;
  for (int cc = 0; cc < 8; ++cc){
    size_t k0 = (size_t)(c0 + cc)*32 + (size_t)g*8;
    bf16x8 x0 = *(const bf16x8*)(Xb + (size_t)r*82944 + k0);
    bf16x8 x1 = *(const bf16x8*)(Xb + (size_t)(r+16)*82944 + k0);
    bf16x8 y0 = *(const bf16x8*)(Yb + (size_t)r*82944 + k0);
    bf16x8 y1 = *(const bf16x8*)(Yb + (size_t)(r+16)*82944 + k0);
    a00 = __builtin_amdgcn_mfma_f32_16x16x32_bf16(x0, y0, a00, 0, 0, 0);
    a01 = __builtin_amdgcn_mfma_f32_16x16x32_bf16(x0, y1, a01, 0, 0, 0);
    a10 = __builtin_amdgcn_mfma_f32_16x16x32_bf16(x1, y0, a10, 0, 0, 0);
    a11 = __builtin_amdgcn_mfma_f32_16x16x32_bf16(x1, y1, a11, 0, 0, 0);
  }
  float* Eb = E + (size_t)b*1024;
  #pragma unroll
  for (int rr = 0; rr < 4; ++rr){
    int row = g*4 + rr;
    atomicAdd(&Eb[row*32 + r],           a00[rr]);
    atomicAdd(&Eb[row*32 + 16 + r],      a01[rr]);
    atomicAdd(&Eb[(row+16)*32 + r],      a10[rr]);
    atomicAdd(&Eb[(row+16)*32 + 16 + r], a11[rr]);
  }
}

__launch_bounds__(256)
__global__ void k_tamapply_mf(const unsigned short* __restrict__ Xbf,
                              const unsigned short* __restrict__ Ybf,
                              const float* __restrict__ e, const float* __restrict__ scp,
                              unsigned short* __restrict__ Pout){
  __shared__ unsigned short yl[32*8*TAPAD];
  __shared__ float al[1024];
  int b = blockIdx.z, tid = threadIdx.x;
  int hw0 = blockIdx.x*8;
  if (tid < 32){
    const float* er = e + (size_t)b*1024 + tid*32;
    float mx = -1e30f, mn = 1e30f;
    for (int j = 0; j < 32; ++j){ mx = fmaxf(mx, er[j]); mn = fminf(mn, er[j]); }
    float zmax = mx - mn;
    float sum = 0.f;
    for (int j = 0; j < 32; ++j){
      float p = __expf((mx - er[j]) - zmax);
      al[tid*32 + j] = p; sum += p;
    }
    float inv = 1.f/sum;
    for (int j = 0; j < 32; ++j) al[tid*32 + j] *= inv;
  }
  const uint4* src = (const uint4*)Ybf + (size_t)b*N2*8;
  #pragma unroll
  for (int it = 0; it < 8; ++it){
    int idx = it*256 + tid;
    int j = idx >> 6, rem = idx & 63, h = rem >> 3, w = rem & 7;
    uint4 v = src[(size_t)(j*1296 + hw0 + h)*8 + w];
    *(uint4*)&yl[(j*8+h)*TAPAD + w*8] = v;
  }
  __syncthreads();
  int t = tid >> 3, h = tid & 7;
  int n = t*1296 + hw0 + h;
  float sc = scp[0];
  const uint4* xr = (const uint4*)Xbf + ((size_t)b*N2 + n)*8;
  float acc[64];
  #pragma unroll
  for (int w = 0; w < 8; ++w){
    uint4 v = xr[w];
    acc[w*8+0] = b2f_lo(v.x); acc[w*8+1] = b2f_hi(v.x);
    acc[w*8+2] = b2f_lo(v.y); acc[w*8+3] = b2f_hi(v.y);
    acc[w*8+4] = b2f_lo(v.z); acc[w*8+5] = b2f_hi(v.z);
    acc[w*8+6] = b2f_lo(v.w); acc[w*8+7] = b2f_hi(v.w);
  }
  const float* ar = &al[t*32];
  for (int j = 0; j < 32; ++j){
    float aj = sc * ar[j];
    const uint4* yr = (const uint4*)&yl[(j*8+h)*TAPAD];
    #pragma unroll
    for (int w = 0; w < 8; ++w){
      uint4 v = yr[w];
      acc[w*8+0] = fmaf(aj, b2f_lo(v.x), acc[w*8+0]);
      acc[w*8+1] = fmaf(aj, b2f_hi(v.x), acc[w*8+1]);
      acc[w*8+2] = fmaf(aj, b2f_lo(v.y), acc[w*8+2]);
      acc[w*8+3] = fmaf(aj, b2f_hi(v.y), acc[w*8+3]);
      acc[w*8+4] = fmaf(aj, b2f_lo(v.z), acc[w*8+4]);
      acc[w*8+5] = fmaf(aj, b2f_hi(v.z), acc[w*8+5]);
      acc[w*8+6] = fmaf(aj, b2f_lo(v.w), acc[w*8+6]);
      acc[w*8+7] = fmaf(aj, b2f_hi(v.w), acc[w*8+7]);
    }
  }
  uint4* orow = (uint4*)Pout + ((size_t)b*N2 + n)*8;
  #pragma unroll
  for (int w = 0; w < 8; ++w){
    uint4 v;
    v.x = (unsigned)f2b(acc[w*8+0]) | ((unsigned)f2b(acc[w*8+1]) << 16);
    v.y = (unsigned)f2b(acc[w*8+2]) | ((unsigned)f2b(acc[w*8+3]) << 16);
    v.z = (unsigned)f2b(acc[w*8+4]) | ((unsigned)f2b(acc[w*8+5]) << 16);
    v.w = (unsigned)f2b(acc[w*8+6]) | ((unsigned)f2b(acc[w*8+7]) << 16);
    orow[w] = v;
  }
}

// ---------------- host ----------------

extern "C" void kernel_launch(void* const* d_in, const int* in_sizes, int n_in,
                              void* d_out, int out_size, void* d_ws, size_t ws_size,
                              hipStream_t stream) {
  const float* x1      = (const float*)d_in[0];
  const float* x2      = (const float*)d_in[1];
  const float* w_conv1 = (const float*)d_in[2];
  const float* g_conv1 = (const float*)d_in[3];
  const float* b_conv1 = (const float*)d_in[4];
  const float* w_conv2 = (const float*)d_in[5];
  const float* g_conv2 = (const float*)d_in[6];
  const float* b_conv2 = (const float*)d_in[7];
  const float* w_tam   = (const float*)d_in[8];
  const float* g_tam   = (const float*)d_in[9];
  const float* b_tam   = (const float*)d_in[10];
  const float* w_cat   = (const float*)d_in[11];
  const float* g_cat   = (const float*)d_in[12];
  const float* b_cat   = (const float*)d_in[13];
  const float* pe_w    = (const float*)d_in[14];
  const float* pe_g    = (const float*)d_in[15];
  const float* pe_b    = (const float*)d_in[16];
  const float* pd_wq   = (const float*)d_in[17];
  const float* pd_bq   = (const float*)d_in[18];
  const float* pd_wk   = (const float*)d_in[19];
  const float* pd_bk   = (const float*)d_in[20];
  const float* pd_wv   = (const float*)d_in[21];
  const float* pd_bv   = (const float*)d_in[22];
  const float* pd_scale= (const float*)d_in[23];
  const float* ce_w    = (const float*)d_in[24];
  const float* ce_g    = (const float*)d_in[25];
  const float* ce_b    = (const float*)d_in[26];
  const float* cd_scale= (const float*)d_in[27];
  const float* te_w    = (const float*)d_in[28];
  const float* te_g    = (const float*)d_in[29];
  const float* te_b    = (const float*)d_in[30];
  const float* td_scale= (const float*)d_in[31];

  float* ws = (float*)d_ws;
  size_t off = 0;
  auto alloc = [&](size_t n){ float* p = ws + off; off += (n + 3) & ~(size_t)3; return p; };
  float* stats = alloc(16384);   // 32 slots x 512   [zeroed]
  float* e_tam = alloc(4096);    //                  [zeroed]
  float* e_cam = alloc(2048);    //                  [zeroed]
  float* p6a   = alloc(9216);    //                  [zeroed]
  float* p6b   = alloc(9216);    //                  [zeroed]
  float* wTce  = alloc(256);
  unsigned short* Wp1  = (unsigned short*)alloc(24576);
  unsigned short* Wp2  = (unsigned short*)alloc(6144);
  unsigned short* Wpt  = (unsigned short*)alloc(6144);
  unsigned short* Wpc  = (unsigned short*)alloc(73728);
  unsigned short* Wpte = (unsigned short*)alloc(2048);
  float* pf2   = alloc(25600);
  float* vb2   = alloc(25600);
  float* KW2   = alloc(25600);
  float* sb2   = alloc(512);
  float* yc2   = alloc(663552);
  float* Mb    = alloc(663552);
  float* A     = alloc(5308416);
  float* Bb    = alloc(5308416);   // contiguous after A
  float* PTEf  = alloc(5308416);
  float* COMB  = alloc(31850496);

  unsigned short* P0 = (unsigned short*)COMB;
  unsigned short* DdBF = (unsigned short*)COMB;                 // te raw bf16
  unsigned short* Dbf  = (unsigned short*)(COMB + 10616832);    // BN'd xt2 bf16
  unsigned short* PTAM = (unsigned short*)(COMB + 15925248);
  unsigned short* RrawBF = (unsigned short*)COMB;               // tam conv raw bf16
  unsigned short* PCAT1 = (unsigned short*)(COMB + 5308416);
  unsigned short* PCAT2 = (unsigned short*)(COMB + 13271040);
  unsigned short* PG4   = (unsigned short*)(COMB + 21233664);   // [4][4][Nn][64] bf16
  unsigned short* R4    = (unsigned short*)A;                   // conv2 raw bf16 (A+Bb dead)
  unsigned short* CATR1 = (unsigned short*)(COMB + 21233664);   // over dead PG4
  unsigned short* CATR2 = (unsigned short*)A;                   // over dead R4
  unsigned short* PTE = (unsigned short*)PTEf;

  const float invc16 = 1.f/(4.f*20736.f);
  const float invc32 = 1.f/(4.f*41472.f);

  // zero stats + e_tam + e_cam + p6a + p6b (contiguous 40960 floats)
  k_zero<<<dim3(160), 256, 0, stream>>>(stats, 40960);
  k_wprep<<<dim3(881), 256, 0, stream>>>(w_conv1, w_conv2, w_tam, w_cat, te_w, ce_w,
                                         Wp1, Wp2, Wpt, Wpc, Wpte, wTce);
  k_convT<<<dim3(81, 1, 8), 256, 0, stream>>>(x1, x2, P0);

  // conv1 A & B merged; boundary planes Mb
  k_mfconv_ab<<<dim3(7,16,8), 256, 0, stream>>>(P0, Wp1, A, Bb, stats);
  k_mfconv<<<dim3(7,2,4), 256, 0, stream>>>(P0, Wp1, Mb, 256, 64, 1, 2, 1, 3, 1, 15, 0, 32, 32, stats + 21*512, 0);
  k_planestats<<<dim3(1,64,2), 256, 0, stream>>>(A, Bb, stats + 22*512, stats + 23*512);
  k_combine<<<dim3(1), 128, 0, stream>>>(stats);
  k_bnT_cc<<<dim3(162,1,4), 256, 0, stream>>>(A, Mb, Bb, stats + 2*512,
                                              g_conv1, b_conv1, invc32, PTE);

  // xt2 = pw_bn_relu(xt1, te_w)
  k_mfconv<<<dim3(7,32,4), 256, 0, stream>>>(PTE, Wpte, (float*)DdBF, 64, 64, 1, 32, 1, 1, 0, 0, 0, 32, 32, stats + 3*512, 1);
  k_bnT<<<dim3(162,1,4), 256, 0, stream>>>(DdBF, stats + 3*512, te_g, te_b, invc32,
                                           Dbf, nullptr, N2, 64, 0, 1);

  // TAM
  k_tamenergy_mf<<<dim3(81, 1, 4), 256, 0, stream>>>(PTE, Dbf, e_tam);
  k_tamapply_mf<<<dim3(162, 1, 4), 256, 0, stream>>>(PTE, Dbf, e_tam, td_scale, PTAM);
  k_mfconv<<<dim3(7,16,4), 256, 0, stream>>>(PTAM, Wpt, (float*)RrawBF, 64, 64, 1, 16, 2, 3, 1, 0, 0, 32, 32, stats + 4*512, 1);
  k_bnT<<<dim3(81,1,4), 256, 0, stream>>>(RrawBF, stats + 4*512, g_tam, b_tam, invc16,
                                          PCAT1, PCAT2, Nn, 192, 128, 1);

  // both branches merged (z=8)
  k_bnrelu_mean2<<<dim3(6,64,8), 256, 0, stream>>>(A, Bb, stats, g_conv1, b_conv1,
                                                   invc16, p6a, p6b);
  k_pamenc1m<<<dim3(50,1,8), 64, 0, stream>>>(p6a, p6b, pe_w, pf2, stats);
  k_pamenc2m<<<dim3(50,1,8), 128, 0, stream>>>(pf2, stats, pe_g, pe_b,
                                               pd_wk, pd_bk, pd_wv, pd_bv, pd_wq, pd_bq,
                                               vb2, KW2, sb2);
  k_pamattnm<<<dim3(81,1,8), 256, 0, stream>>>(A, Bb, KW2, sb2, vb2, pd_scale, PG4);
  k_tconvm<<<dim3(6,16,8), dim3(4,64), 0, stream>>>(A, Bb, wTce, yc2, stats);
  k_camenergy2m<<<dim3(81,1,8), 256, 0, stream>>>(A, Bb, yc2, stats, ce_g, ce_b,
                                                  invc16, e_cam);
  k_camapplyTm<<<dim3(81,1,8), 256, 0, stream>>>(A, Bb, yc2, stats, ce_g, ce_b,
                                                 invc16, e_cam, cd_scale, PG4);

  // all four conv2's in one launch (A/Bb now dead -> R4 reuses them)
  k_mfconv4<<<dim3(7,16,16), 256, 0, stream>>>(PG4, Wp2, R4, stats);
  k_bnT4<<<dim3(81,1,16), 256, 0, stream>>>(R4, stats, g_conv2, b_conv2, invc16,
                                            PCAT1, PCAT2);

  // cat convs: wave-per-chunk variant (B-panel shared via L1) -> bf16 raws -> BN out
  k_mfconvcat2<<<dim3(27,16,8), 256, 0, stream>>>(PCAT1, PCAT2, Wpc, CATR1, CATR2, stats);
  k_bnrelu_out<<<dim3(11, 256, 8), 256, 0, stream>>>(CATR1, CATR2, stats + 19*512,
                                                     g_cat, b_cat, invc16, (float*)d_out);
}

// Round 14
// 741.327 us; speedup vs baseline: 1.2563x; 1.2563x over previous
//
#include <hip/hip_runtime.h>

#define HW 1296
#define Nn 20736
#define N2 41472
#define TAPAD 72

typedef short bf16x8 __attribute__((ext_vector_type(8)));
typedef float f32x4 __attribute__((ext_vector_type(4)));

__device__ inline unsigned short f2b(float f){
  union { float f; unsigned u; } v; v.f = f;
  unsigned r = v.u + 0x7FFF + ((v.u >> 16) & 1);
  return (unsigned short)(r >> 16);
}
__device__ inline float b2f(unsigned short u){
  union { unsigned u; float f; } v; v.u = ((unsigned)u) << 16; return v.f;
}
__device__ inline float b2f_lo(unsigned u){
  union { unsigned u; float f; } v; v.u = u << 16; return v.f;
}
__device__ inline float b2f_hi(unsigned u){
  union { unsigned u; float f; } v; v.u = u & 0xffff0000u; return v.f;
}

__device__ __forceinline__ void pack_pairs(const float* a, unsigned* vals){
  #pragma unroll
  for (int i = 0; i < 32; ++i)
    vals[i] = (unsigned)f2b(a[2*i]) | ((unsigned)f2b(a[2*i+1]) << 16);
}

// LDS-transpose staged coalesced write (256 threads, each owns a 64-bf16 row)
__device__ __forceinline__ void staged_write(unsigned* lds, int tid, const unsigned* vals,
                                             uint4* o4, size_t R0, int rowu4, int cw,
                                             uint4* o4b){
  #pragma unroll
  for (int i = 0; i < 32; ++i) lds[tid*33 + i] = vals[i];
  __syncthreads();
  #pragma unroll
  for (int k = 0; k < 8; ++k){
    int j = k*256 + tid;
    int nn = j >> 3, w = j & 7;
    int base = nn*33 + w*4;
    uint4 v;
    v.x = lds[base]; v.y = lds[base+1]; v.z = lds[base+2]; v.w = lds[base+3];
    size_t oidx = (R0 + (size_t)nn)*(size_t)rowu4 + cw + w;
    o4[oidx] = v;
    if (o4b) o4b[oidx] = v;
  }
  __syncthreads();
}

// ---------------- utility ----------------

__global__ void k_zero(float* p, int n){
  int i = blockIdx.x*blockDim.x + threadIdx.x;
  if (i < n) p[i] = 0.f;
}

__device__ __forceinline__ void wpack_one(int e, const float* w, unsigned short* wp,
                                          int Cout, int Cin, int KT){
  int Kt32 = (Cin*KT) >> 5;
  int j    = e & 7;
  int lane = (e >> 3) & 63;
  int rest = e >> 9;
  int ks   = rest % Kt32;
  int mt   = rest / Kt32;
  int m  = mt*16 + (lane & 15);
  int k  = ks*32 + (lane >> 4)*8 + j;
  int dt = k / Cin, ci = k - dt*Cin;
  wp[e] = f2b(w[((size_t)m*Cin + ci)*KT + dt]);
}

__global__ void k_wprep(const float* w1, const float* w2, const float* wt,
                        const float* wc, const float* wte, const float* wce,
                        unsigned short* Wp1, unsigned short* Wp2, unsigned short* Wpt,
                        unsigned short* Wpc, unsigned short* Wpte, float* wTce){
  int idx = blockIdx.x*256 + threadIdx.x;
  if (idx < 49152){ wpack_one(idx, w1, Wp1, 64, 256, 3); return; }
  idx -= 49152;
  if (idx < 12288){ wpack_one(idx, w2, Wp2, 64, 64, 3); return; }
  idx -= 12288;
  if (idx < 12288){ wpack_one(idx, wt, Wpt, 64, 64, 3); return; }
  idx -= 12288;
  if (idx < 147456){ wpack_one(idx, wc, Wpc, 256, 192, 3); return; }
  idx -= 147456;
  if (idx < 4096){ wpack_one(idx, wte, Wpte, 64, 64, 1); return; }
  idx -= 4096;
  if (idx < 256){
    int o = idx / 64, i = idx % 64;
    wTce[i*4 + o] = wce[idx];
  }
}

// f32 [b][256][Nn] (x1 & x2) -> bf16 P-layout [b][plane][hw][256]; z<4: x1, z>=4: x2
__global__ void k_convT(const float* __restrict__ x1, const float* __restrict__ x2,
                        unsigned short* __restrict__ Pb){
  __shared__ unsigned lds[8448];
  int tid = threadIdx.x, z = blockIdx.z;
  int b = z & 3;
  const float* x = (z < 4) ? x1 : x2;
  int p0 = (z < 4) ? 0 : 16;
  int n0 = blockIdx.x*256, n = n0 + tid;
  const float* xb = x + (size_t)b*256*Nn + n;
  size_t R0 = (size_t)(b*32 + p0)*1296 + n0;
  uint4* o4 = (uint4*)Pb;
  for (int c0 = 0; c0 < 256; c0 += 64){
    float a[64];
    #pragma unroll
    for (int c = 0; c < 64; ++c) a[c] = xb[(size_t)(c0 + c)*Nn];
    unsigned vals[32];
    pack_pairs(a, vals);
    staged_write(lds, tid, vals, o4, R0, 32, c0 >> 3, nullptr);
  }
}

// ---------------- shared MFMA conv body (64-out-ch chunk) + fused BN-stats ----------------
__device__ __forceinline__ void mf_body(const unsigned short* __restrict__ P,
                                        const unsigned short* __restrict__ Wp,
                                        void* __restrict__ out, float* __restrict__ sums,
                                        float* sredf,
                                        int Cin, int Cout, int mz, int b,
                                        int Tout, int stride, int KT, int pad,
                                        int p0, int plo, int phi, int PT, int obf)
{
  int lane = threadIdx.x & 63;
  int wave = threadIdx.x >> 6;
  int tile = blockIdx.x*4 + wave;
  bool valid = (tile < 27);
  int t = blockIdx.y;
  int col = lane & 15, grp = lane >> 4;
  int Kt32 = (KT*Cin) >> 5;
  f32x4 acc[4][3];
  #pragma unroll
  for (int i = 0; i < 4; ++i)
    #pragma unroll
    for (int j = 0; j < 3; ++j) acc[i][j] = (f32x4){0.f, 0.f, 0.f, 0.f};
  if (valid){
    int hw0 = tile*48 + col;
    const unsigned short* wbase = Wp + ((size_t)(mz*4)*Kt32)*512 + lane*8;
    for (int dt = 0; dt < KT; ++dt){
      int p = t*stride + dt - pad + p0;
      if (p < plo || p >= phi) continue;
      const unsigned short* Pp = P + ((size_t)(b*PT + p)*1296 + hw0)*Cin + grp*8;
      int nCk = Cin >> 5;
      int ksg = (dt*Cin) >> 5;
      for (int kc = 0; kc < nCk; ++kc){
        bf16x8 bf0 = *(const bf16x8*)(Pp + (size_t)0*Cin  + kc*32);
        bf16x8 bf1 = *(const bf16x8*)(Pp + (size_t)16*Cin + kc*32);
        bf16x8 bf2 = *(const bf16x8*)(Pp + (size_t)32*Cin + kc*32);
        #pragma unroll
        for (int mf = 0; mf < 4; ++mf){
          bf16x8 af = *(const bf16x8*)(wbase + ((size_t)mf*Kt32 + ksg + kc)*512);
          acc[mf][0] = __builtin_amdgcn_mfma_f32_16x16x32_bf16(af, bf0, acc[mf][0], 0, 0, 0);
          acc[mf][1] = __builtin_amdgcn_mfma_f32_16x16x32_bf16(af, bf1, acc[mf][1], 0, 0, 0);
          acc[mf][2] = __builtin_amdgcn_mfma_f32_16x16x32_bf16(af, bf2, acc[mf][2], 0, 0, 0);
        }
      }
    }
    size_t cs = (size_t)Tout*1296;
    size_t obase = ((size_t)(b*Cout + mz*64 + grp*4))*cs + (size_t)t*1296;
    if (obf){
      unsigned short* o16 = (unsigned short*)out;
      #pragma unroll
      for (int mf = 0; mf < 4; ++mf)
        #pragma unroll
        for (int f = 0; f < 3; ++f){
          int hw = tile*48 + f*16 + col;
          #pragma unroll
          for (int r = 0; r < 4; ++r)
            o16[obase + (size_t)(mf*16 + r)*cs + hw] = f2b(acc[mf][f][r]);
        }
    } else {
      float* o32 = (float*)out;
      #pragma unroll
      for (int mf = 0; mf < 4; ++mf)
        #pragma unroll
        for (int f = 0; f < 3; ++f){
          int hw = tile*48 + f*16 + col;
          #pragma unroll
          for (int r = 0; r < 4; ++r)
            o32[obase + (size_t)(mf*16 + r)*cs + hw] = acc[mf][f][r];
        }
    }
  }
  float s[16], q[16];
  #pragma unroll
  for (int mf = 0; mf < 4; ++mf)
    #pragma unroll
    for (int r = 0; r < 4; ++r){
      float v0 = acc[mf][0][r], v1 = acc[mf][1][r], v2 = acc[mf][2][r];
      s[mf*4+r] = v0 + v1 + v2;
      q[mf*4+r] = v0*v0 + v1*v1 + v2*v2;
    }
  #pragma unroll
  for (int m = 1; m <= 8; m <<= 1){
    #pragma unroll
    for (int j = 0; j < 16; ++j){
      s[j] += __shfl_xor(s[j], m);
      q[j] += __shfl_xor(q[j], m);
    }
  }
  if (col == 0){
    #pragma unroll
    for (int j = 0; j < 16; ++j){
      sredf[((0*4 + wave)*4 + grp)*16 + j] = s[j];
      sredf[((1*4 + wave)*4 + grp)*16 + j] = q[j];
    }
  }
  __syncthreads();
  int tid = threadIdx.x;
  if (tid < 128){
    int stat = tid >> 6, ch = tid & 63;
    int rr = ch & 3, gg = (ch >> 2) & 3, mm = ch >> 4;
    int j = mm*4 + rr;
    float v = sredf[((stat*4 + 0)*4 + gg)*16 + j] + sredf[((stat*4 + 1)*4 + gg)*16 + j]
            + sredf[((stat*4 + 2)*4 + gg)*16 + j] + sredf[((stat*4 + 3)*4 + gg)*16 + j];
    atomicAdd(&sums[stat*Cout + mz*64 + ch], v);
  }
}

// generic (te / tam / Mb convs)
__launch_bounds__(256)
__global__ void k_mfconv(const unsigned short* __restrict__ P, const unsigned short* __restrict__ Wp,
                         float* __restrict__ out, int Cin, int Cout, int Mz,
                         int Tout, int stride, int KT, int pad, int p0, int plo, int phi, int PT,
                         float* __restrict__ sums, int obf)
{
  __shared__ float sred[2*4*4*16];
  int bz = blockIdx.z; int b = bz / Mz; int mz = bz - b*Mz;
  mf_body(P, Wp, out, sums, sred, Cin, Cout, mz, b, Tout, stride, KT, pad,
          p0, plo, phi, PT, obf);
}

// conv1 A & B merged (z in [0,8): which = z>>2, b = z&3)
__launch_bounds__(256)
__global__ void k_mfconv_ab(const unsigned short* __restrict__ P, const unsigned short* __restrict__ Wp,
                            float* __restrict__ A, float* __restrict__ Bb,
                            float* __restrict__ stats)
{
  __shared__ float sred[2*4*4*16];
  int bz = blockIdx.z; int which = bz >> 2; int b = bz & 3;
  float* out = which ? Bb : A;
  float* sums = stats + (size_t)which*512;
  int p0 = which*16;
  mf_body(P, Wp, out, sums, sred, 256, 64, 0, b, 16, 1, 3, 1, p0, p0, p0+16, 32, 0);
}

// conv2 over PG4 (16 pseudo-batches = stage*4+b), bf16 out
__launch_bounds__(256)
__global__ void k_mfconv4(const unsigned short* __restrict__ PG4, const unsigned short* __restrict__ Wp,
                          unsigned short* __restrict__ Rout, float* __restrict__ stats)
{
  __shared__ float sred[2*4*4*16];
  int pb = blockIdx.z;
  int stage = pb >> 2;
  int slot = (stage < 2) ? (13 + stage) : (15 + stage);
  mf_body(PG4, Wp, Rout, stats + (size_t)slot*512, sred, 64, 64, 0, pb,
          16, 1, 3, 1, 0, 0, 16, 16, 1);
}

// both cat convs merged (z in [0,32)) — round-12 proven version
__launch_bounds__(256)
__global__ void k_mfconvcat(const unsigned short* __restrict__ PCAT1, const unsigned short* __restrict__ PCAT2,
                            const unsigned short* __restrict__ Wp,
                            unsigned short* __restrict__ CATR1, unsigned short* __restrict__ CATR2,
                            float* __restrict__ stats)
{
  __shared__ float sred[2*4*4*16];
  int bz = blockIdx.z;
  int which = bz >> 4; int rem = bz & 15;
  int b = rem >> 2; int mz = rem & 3;
  const unsigned short* P = which ? PCAT2 : PCAT1;
  unsigned short* out = which ? CATR2 : CATR1;
  float* sums = stats + (size_t)(19 + which)*512;
  mf_body(P, Wp, out, sums, sred, 192, 256, mz, b, 16, 1, 3, 1, 0, 0, 16, 16, 1);
}

// ---------------- ce pointwise conv 64->4 merged (z in [0,8)) ----------------
__global__ void k_tconvm(const float* __restrict__ A, const float* __restrict__ Bb,
                         const float* __restrict__ wT,
                         float* __restrict__ yc2, float* __restrict__ stats)
{
  __shared__ float r1[4][64], r2[4][64];
  int z = blockIdx.z;
  int which = z >> 2, b = z & 3;
  const float* xA = which ? Bb : A;
  float* out = yc2 + (size_t)which*331776;
  float* sums = stats + (size_t)(15 + which)*512;
  int o  = threadIdx.x;  // 4
  int ty = threadIdx.y;  // 64
  int t  = blockIdx.y;
  int hw4 = blockIdx.x*64 + ty;
  bool valid = (hw4 < 324);
  float4 acc = make_float4(0.f,0.f,0.f,0.f);
  if (valid){
    const float4* xr = (const float4*)xA + ((size_t)b*64*16 + t)*324 + hw4;
    const float* wp  = wT + o;
    size_t xstep = (size_t)16*324;
    for (int i = 0; i < 64; ++i){
      float4 xv = *xr;
      float  wv = *wp;
      acc.x = fmaf(wv, xv.x, acc.x);
      acc.y = fmaf(wv, xv.y, acc.y);
      acc.z = fmaf(wv, xv.z, acc.z);
      acc.w = fmaf(wv, xv.w, acc.w);
      xr += xstep; wp += 4;
    }
    float4* op = (float4*)out + ((size_t)(b*4 + o)*16 + t)*324 + hw4;
    *op = acc;
  }
  r1[o][ty] = acc.x + acc.y + acc.z + acc.w;
  r2[o][ty] = acc.x*acc.x + acc.y*acc.y + acc.z*acc.z + acc.w*acc.w;
  __syncthreads();
  int tid = threadIdx.y*4 + threadIdx.x;
  for (int k = 32; k > 0; k >>= 1){
    if (ty < k){
      r1[o][ty] += r1[o][ty+k];
      r2[o][ty] += r2[o][ty+k];
    }
    __syncthreads();
  }
  if (tid < 4) atomicAdd(&sums[tid],     r1[tid][0]);
  else if (tid < 8) atomicAdd(&sums[tid], r2[tid-4][0]);
}

// ---------------- BN ----------------

__global__ void k_planestats(const float* __restrict__ A, const float* __restrict__ B,
                             float* __restrict__ s22, float* __restrict__ s23){
  int which = blockIdx.z, c = blockIdx.y, tid = threadIdx.x;
  const float* src = which ? B : A;
  int toff = which ? 0 : 15;
  float* dst = which ? s23 : s22;
  float s = 0.f, q = 0.f;
  for (int idx = tid; idx < 4*1296; idx += 256){
    int b = idx / 1296, hw = idx - b*1296;
    float v = src[(((size_t)b*64 + c)*16 + toff)*1296 + hw];
    s += v; q += v*v;
  }
  __shared__ float r1[256], r2[256];
  r1[tid] = s; r2[tid] = q; __syncthreads();
  for (int k = 128; k > 0; k >>= 1){
    if (tid < k){ r1[tid] += r1[tid+k]; r2[tid] += r2[tid+k]; }
    __syncthreads();
  }
  if (tid == 0){ dst[c] = r1[0]; dst[64 + c] = r2[0]; }
}

__global__ void k_combine(float* stats){
  int i = threadIdx.x;
  if (i < 128)
    stats[2*512 + i] = stats[0*512 + i] + stats[1*512 + i]
                     - stats[22*512 + i] - stats[23*512 + i] + stats[21*512 + i];
}

// BN+ReLU from bf16 raw cat outputs -> f32 d_out halves; z: b + 4*which
__global__ void k_bnrelu_out(const unsigned short* __restrict__ x1bf,
                             const unsigned short* __restrict__ x2bf,
                             const float* __restrict__ stats19,
                             const float* __restrict__ g,
                             const float* __restrict__ bet, float invc,
                             float* __restrict__ out)
{
  int z = blockIdx.z;
  int b = z & 3, which = z >> 2;
  const unsigned short* xbf = which ? x2bf : x1bf;
  const float* sums = stats19 + (size_t)which*512;
  float* op = out + (size_t)which*4*256*Nn;
  int c = blockIdx.y;
  int n8 = blockIdx.x*256 + threadIdx.x;
  if (n8 >= 2592) return;
  float m  = sums[c]*invc;
  float v  = fmaxf(sums[256+c]*invc - m*m, 0.f);
  float sc = g[c]*rsqrtf(v + 1e-5f);
  float bb = bet[c] - m*sc;
  size_t base = ((size_t)(b*256 + c))*Nn + (size_t)n8*8;
  uint4 u = *(const uint4*)(xbf + base);
  float4 o0, o1;
  o0.x = fmaxf(fmaf(b2f_lo(u.x), sc, bb), 0.f);
  o0.y = fmaxf(fmaf(b2f_hi(u.x), sc, bb), 0.f);
  o0.z = fmaxf(fmaf(b2f_lo(u.y), sc, bb), 0.f);
  o0.w = fmaxf(fmaf(b2f_hi(u.y), sc, bb), 0.f);
  o1.x = fmaxf(fmaf(b2f_lo(u.z), sc, bb), 0.f);
  o1.y = fmaxf(fmaf(b2f_hi(u.z), sc, bb), 0.f);
  o1.z = fmaxf(fmaf(b2f_lo(u.w), sc, bb), 0.f);
  o1.w = fmaxf(fmaf(b2f_hi(u.w), sc, bb), 0.f);
  *(float4*)(op + base) = o0;
  *(float4*)(op + base + 4) = o1;
}

// merged BN+ReLU in place on A & Bb + p6 accumulation (z in [0,8))
__global__ void k_bnrelu_mean2(float* __restrict__ A, float* __restrict__ Bb,
                               const float* __restrict__ stats,
                               const float* __restrict__ g, const float* __restrict__ bet,
                               float invc, float* __restrict__ p6a, float* __restrict__ p6b)
{
  __shared__ float p6loc[36];
  int z = blockIdx.z;
  int which = z >> 2, b = z & 3;
  float* x = which ? Bb : A;
  const float* sums = stats + (size_t)which*512;
  float* p6 = which ? p6b : p6a;
  int tid = threadIdx.x;
  if (tid < 36) p6loc[tid] = 0.f;
  __syncthreads();
  int hw = blockIdx.x*256 + tid;
  int c = blockIdx.y;
  if (hw < 1296){
    float m  = sums[c]*invc;
    float v  = fmaxf(sums[64+c]*invc - m*m, 0.f);
    float sc = g[c]*rsqrtf(v + 1e-5f);
    float bb = bet[c] - m*sc;
    float* xb = x + ((size_t)(b*64 + c)*16)*1296 + hw;
    float s = 0.f;
    #pragma unroll
    for (int t = 0; t < 16; ++t){
      float val = fmaxf(fmaf(xb[(size_t)t*1296], sc, bb), 0.f);
      xb[(size_t)t*1296] = val;
      s += val;
    }
    int h = hw / 36, w = hw - h*36;
    atomicAdd(&p6loc[(h/6)*6 + (w/6)], s*(1.f/16.f));
  }
  __syncthreads();
  if (tid < 36) atomicAdd(&p6[((size_t)(b*64 + c))*36 + tid], p6loc[tid]);
}

// BN+ReLU on raw [b][64][L] (f32 or bf16 per xbf) -> bf16 P rows [b][n][outC] at coff
__global__ void k_bnT(const void* __restrict__ xraw, const float* __restrict__ sums,
                      const float* __restrict__ g, const float* __restrict__ bet, float invc,
                      unsigned short* __restrict__ P1, unsigned short* __restrict__ P2,
                      int L, int outC, int coff, int xbf)
{
  __shared__ unsigned lds[8448];
  int tid = threadIdx.x, b = blockIdx.z;
  int n0 = blockIdx.x*256, n = n0 + tid;
  float a[64];
  if (xbf){
    const unsigned short* xb = (const unsigned short*)xraw + (size_t)b*64*L + n;
    #pragma unroll
    for (int c = 0; c < 64; ++c){
      float m  = sums[c]*invc;
      float vv = fmaxf(sums[64+c]*invc - m*m, 0.f);
      float sc = g[c]*rsqrtf(vv + 1e-5f);
      float bb = bet[c] - m*sc;
      a[c] = fmaxf(fmaf(b2f(xb[(size_t)c*L]), sc, bb), 0.f);
    }
  } else {
    const float* xb = (const float*)xraw + (size_t)b*64*L + n;
    #pragma unroll
    for (int c = 0; c < 64; ++c){
      float m  = sums[c]*invc;
      float vv = fmaxf(sums[64+c]*invc - m*m, 0.f);
      float sc = g[c]*rsqrtf(vv + 1e-5f);
      float bb = bet[c] - m*sc;
      a[c] = fmaxf(fmaf(xb[(size_t)c*L], sc, bb), 0.f);
    }
  }
  unsigned vals[32];
  pack_pairs(a, vals);
  staged_write(lds, tid, vals, (uint4*)P1, (size_t)b*L + n0, outC >> 3, coff >> 3,
               P2 ? (uint4*)P2 : nullptr);
}

// merged conv2 BN -> concat buffers (z in [0,16): stage = z>>2, b = z&3)
__global__ void k_bnT4(const unsigned short* __restrict__ R4, const float* __restrict__ stats,
                       const float* __restrict__ g, const float* __restrict__ bet, float invc,
                       unsigned short* __restrict__ PCAT1, unsigned short* __restrict__ PCAT2)
{
  __shared__ unsigned lds[8448];
  int z = blockIdx.z;
  int stage = z >> 2, b = z & 3;
  int slot = (stage < 2) ? (13 + stage) : (15 + stage);
  const float* sums = stats + (size_t)slot*512;
  unsigned short* P1 = (stage == 0 || stage == 3) ? PCAT1 : PCAT2;
  int cw = (stage < 2) ? 0 : 8;
  int tid = threadIdx.x;
  int n0 = blockIdx.x*256, n = n0 + tid;
  const unsigned short* xb = R4 + (size_t)z*64*Nn + n;
  float a[64];
  #pragma unroll
  for (int c = 0; c < 64; ++c){
    float m  = sums[c]*invc;
    float vv = fmaxf(sums[64+c]*invc - m*m, 0.f);
    float sc = g[c]*rsqrtf(vv + 1e-5f);
    float bb = bet[c] - m*sc;
    a[c] = fmaxf(fmaf(b2f(xb[(size_t)c*Nn]), sc, bb), 0.f);
  }
  unsigned vals[32];
  pack_pairs(a, vals);
  staged_write(lds, tid, vals, (uint4*)P1, (size_t)b*Nn + n0, 24, cw, nullptr);
}

// composed-concat BN+ReLU -> bf16 PTE [b][n][64]
__global__ void k_bnT_cc(const float* __restrict__ A, const float* __restrict__ M,
                         const float* __restrict__ B, const float* __restrict__ sums,
                         const float* __restrict__ g, const float* __restrict__ bet,
                         float invc, unsigned short* __restrict__ P1)
{
  __shared__ unsigned lds[8448];
  int tid = threadIdx.x, b = blockIdx.z;
  int n0 = blockIdx.x*256, n = n0 + tid;
  int t = n / 1296, hw = n - t*1296;
  const float* src; size_t cstride;
  if (t < 15){ src = A + ((size_t)(b*64)*16 + t)*1296 + hw; cstride = (size_t)16*1296; }
  else if (t < 17){ src = M + ((size_t)(b*64)*2 + (t-15))*1296 + hw; cstride = (size_t)2*1296; }
  else { src = B + ((size_t)(b*64)*16 + (t-16))*1296 + hw; cstride = (size_t)16*1296; }
  float a[64];
  #pragma unroll
  for (int c = 0; c < 64; ++c){
    float m  = sums[c]*invc;
    float vv = fmaxf(sums[64+c]*invc - m*m, 0.f);
    float sc = g[c]*rsqrtf(vv + 1e-5f);
    float bb = bet[c] - m*sc;
    a[c] = fmaxf(fmaf(src[c*cstride], sc, bb), 0.f);
  }
  unsigned vals[32];
  pack_pairs(a, vals);
  staged_write(lds, tid, vals, (uint4*)P1, (size_t)b*N2 + n0, 8, 0, nullptr);
}

// ---------------- PAM (merged, z in [0,8): which = z>>2, b = z&3) ----------------

__global__ void k_pamenc1m(const float* __restrict__ p6a, const float* __restrict__ p6b,
                           const float* __restrict__ pe_w,
                           float* __restrict__ pf2, float* __restrict__ stats){
  __shared__ float psh[64];
  int z = blockIdx.z;
  int which = z >> 2, b = z & 3;
  const float* p6 = which ? p6b : p6a;
  float* sl = stats + (size_t)(which ? 9 : 5)*512;
  float* pf = pf2 + (size_t)which*12800;
  int cell = blockIdx.x;
  int o = threadIdx.x;
  int s, off;
  if (cell < 1){ s=1; off=0; } else if (cell < 5){ s=2; off=1; }
  else if (cell < 14){ s=3; off=5; } else { s=6; off=14; }
  int local = cell - off, ph = local/s, pw = local%s;
  int bs = 6/s;
  const float* pp = p6 + ((size_t)(b*64 + o))*36;
  float sum = 0.f;
  for (int i = 0; i < bs; ++i)
    for (int j = 0; j < bs; ++j)
      sum += pp[(ph*bs + i)*6 + (pw*bs + j)];
  psh[o] = sum * ((float)(s*s) * (1.f/1296.f));
  __syncthreads();
  int grp = (cell < 1) ? 0 : (cell < 5) ? 1 : (cell < 14) ? 2 : 3;
  const float* w = pe_w + (size_t)grp*4096 + o*64;
  float acc = 0.f;
  #pragma unroll
  for (int i = 0; i < 64; ++i) acc = fmaf(w[i], psh[i], acc);
  pf[((size_t)b*64 + o)*50 + cell] = acc;
  atomicAdd(&sl[grp*128 + o], acc);
  atomicAdd(&sl[grp*128 + 64 + o], acc*acc);
}

__launch_bounds__(128)
__global__ void k_pamenc2m(const float* __restrict__ pf2, float* __restrict__ stats,
                           const float* __restrict__ pe_g, const float* __restrict__ pe_b,
                           const float* __restrict__ wk, const float* __restrict__ bk,
                           const float* __restrict__ wv, const float* __restrict__ bv,
                           const float* __restrict__ wq, const float* __restrict__ bq,
                           float* __restrict__ vb2, float* __restrict__ KW2,
                           float* __restrict__ sb2)
{
  __shared__ float yk[64];
  __shared__ float kbl[16];
  int z = blockIdx.z;
  int which = z >> 2, b = z & 3;
  const float* pf = pf2 + (size_t)which*12800;
  const float* sl = stats + (size_t)(which ? 9 : 5)*512;
  float* vb = vb2 + (size_t)which*12800;
  float* KW = KW2 + (size_t)which*12800;
  float* sb = sb2 + (size_t)which*256;
  int k = blockIdx.x;
  int tid = threadIdx.x;
  int grp = (k < 1) ? 0 : (k < 5) ? 1 : (k < 14) ? 2 : 3;
  const float ss2[4] = {1.f, 4.f, 9.f, 36.f};
  if (tid < 64){
    float invc = 1.f/(4.f*ss2[grp]);
    float m = sl[grp*128 + tid]*invc;
    float var = fmaxf(sl[grp*128 + 64 + tid]*invc - m*m, 0.f);
    float sc = pe_g[grp*64 + tid]*rsqrtf(var + 1e-5f);
    float sh = pe_b[grp*64 + tid] - m*sc;
    yk[tid] = fmaxf(fmaf(pf[((size_t)b*64 + tid)*50 + k], sc, sh), 0.f);
  }
  __syncthreads();
  if (tid < 16){
    float s = bk[tid];
    #pragma unroll
    for (int c = 0; c < 64; ++c) s = fmaf(wk[tid*64 + c], yk[c], s);
    kbl[tid] = s;
  } else if (tid < 80){
    int c = tid - 16;
    float s = bv[c];
    #pragma unroll
    for (int i = 0; i < 64; ++i) s = fmaf(wv[c*64 + i], yk[i], s);
    vb[((size_t)b*50 + k)*64 + c] = s;
  }
  __syncthreads();
  if (tid < 64){
    float s = 0.f;
    #pragma unroll
    for (int o = 0; o < 16; ++o) s = fmaf(kbl[o], wq[o*64 + tid], s);
    KW[((size_t)b*50 + k)*64 + tid] = s;
  } else if (tid == 64){
    float s = 0.f;
    #pragma unroll
    for (int o = 0; o < 16; ++o) s = fmaf(kbl[o], bq[o], s);
    sb[(size_t)b*50 + k] = s;
  }
}

// merged pamattn: z in [0,8): which = z>>2, b = z&3; out -> PG4 stage `which`
__launch_bounds__(256, 1)
__global__ void k_pamattnm(const float* __restrict__ A, const float* __restrict__ Bb,
                           const float* __restrict__ KW2, const float* __restrict__ sb2,
                           const float* __restrict__ vb2, const float* __restrict__ scp,
                           unsigned short* __restrict__ PG4)
{
  __shared__ unsigned smem_u[8448];
  float* smem = (float*)smem_u;
  int z = blockIdx.z;
  int which = z >> 2, b = z & 3;
  const float* x = which ? Bb : A;
  const float* KW = KW2 + (size_t)which*12800;
  const float* sbb = sb2 + (size_t)which*256;
  const float* vbuf = vb2 + (size_t)which*12800;
  int tid = threadIdx.x;
  for (int i = tid; i < 3200; i += 256){
    smem[i]        = KW[(size_t)b*3200 + i];
    smem[3200 + i] = vbuf[(size_t)b*3200 + i];
  }
  if (tid < 50) smem[6400 + tid] = sbb[(size_t)b*50 + tid];
  __syncthreads();
  int n0 = blockIdx.x*256;
  int n = n0 + tid;
  const float* xb = x + (size_t)b*64*Nn + n;
  float xv[64];
  #pragma unroll
  for (int c = 0; c < 64; ++c) xv[c] = xb[(size_t)c*Nn];
  float s[50];
  const float4* kw4 = (const float4*)smem;
  #pragma unroll
  for (int k = 0; k < 50; ++k){
    float t = smem[6400 + k];
    #pragma unroll
    for (int c4 = 0; c4 < 16; ++c4){
      float4 kw = kw4[k*16 + c4];
      t = fmaf(xv[c4*4+0], kw.x, t);
      t = fmaf(xv[c4*4+1], kw.y, t);
      t = fmaf(xv[c4*4+2], kw.z, t);
      t = fmaf(xv[c4*4+3], kw.w, t);
    }
    s[k] = t;
  }
  float mx = -1e30f;
  #pragma unroll
  for (int k = 0; k < 50; ++k) mx = fmaxf(mx, s[k]);
  float sum = 0.f;
  #pragma unroll
  for (int k = 0; k < 50; ++k){ float p = __expf(s[k]-mx); s[k] = p; sum += p; }
  float sc = scp[0]/sum;
  const float4* vl4 = (const float4*)(smem + 3200);
  #pragma unroll
  for (int k = 0; k < 50; ++k){
    float pk = sc * s[k];
    #pragma unroll
    for (int c4 = 0; c4 < 16; ++c4){
      float4 v = vl4[k*16 + c4];
      xv[c4*4+0] = fmaf(pk, v.x, xv[c4*4+0]);
      xv[c4*4+1] = fmaf(pk, v.y, xv[c4*4+1]);
      xv[c4*4+2] = fmaf(pk, v.z, xv[c4*4+2]);
      xv[c4*4+3] = fmaf(pk, v.w, xv[c4*4+3]);
    }
  }
  __syncthreads();
  unsigned vals[32];
  pack_pairs(xv, vals);
  staged_write(smem_u, tid, vals, (uint4*)PG4, (size_t)(which*4 + b)*Nn + n0, 8, 0, nullptr);
}

// ---------------- CAM (merged) ----------------

__global__ void k_camenergy2m(const float* __restrict__ A, const float* __restrict__ Bb,
                              const float* __restrict__ yc2, const float* __restrict__ stats,
                              const float* __restrict__ ce_g, const float* __restrict__ ce_b,
                              float invc, float* __restrict__ e_cam){
  __shared__ float yl[4][256];
  int z = blockIdx.z;
  int which = z >> 2, b = z & 3;
  const float* x = which ? Bb : A;
  const float* yc = yc2 + (size_t)which*331776;
  const float* sums = stats + (size_t)(15 + which)*512;
  float* e = e_cam + (size_t)which*1024;
  int tid = threadIdx.x;
  int n0 = blockIdx.x*256;
  #pragma unroll
  for (int k = 0; k < 4; ++k){
    float m  = sums[k]*invc;
    float vv = fmaxf(sums[4+k]*invc - m*m, 0.f);
    float sck = ce_g[k]*rsqrtf(vv + 1e-5f);
    float bbk = ce_b[k] - m*sck;
    float raw = yc[((size_t)b*4+k)*Nn + n0 + tid];
    yl[k][tid] = fmaxf(fmaf(raw, sck, bbk), 0.f);
  }
  __syncthreads();
  int c = tid & 63, ks = tid >> 6;
  const float* xr = x + (size_t)(b*64+c)*Nn + n0;
  const float* yr = yl[ks];
  float acc = 0.f;
  #pragma unroll 8
  for (int i = 0; i < 256; ++i) acc = fmaf(xr[i], yr[i], acc);
  atomicAdd(&e[((size_t)(b*64)+c)*4 + ks], acc);
}

// merged camapply: out -> PG4 stage 2+which
__global__ void k_camapplyTm(const float* __restrict__ A, const float* __restrict__ Bb,
                             const float* __restrict__ yc2, const float* __restrict__ stats,
                             const float* __restrict__ ce_g, const float* __restrict__ ce_b,
                             float invc, const float* __restrict__ e_cam,
                             const float* __restrict__ scp, unsigned short* __restrict__ PG4){
  __shared__ float pw[64][4];
  __shared__ unsigned lds[8448];
  int z = blockIdx.z;
  int which = z >> 2, b = z & 3;
  const float* x = which ? Bb : A;
  const float* yc = yc2 + (size_t)which*331776;
  const float* sums = stats + (size_t)(15 + which)*512;
  const float* e = e_cam + (size_t)which*1024;
  int tid = threadIdx.x;
  if (tid < 64){
    const float* er = e + (size_t)(b*64+tid)*4;
    float e0=er[0], e1=er[1], e2=er[2], e3=er[3];
    float mx = fmaxf(fmaxf(e0,e1), fmaxf(e2,e3));
    float z0=mx-e0, z1=mx-e1, z2=mx-e2, z3=mx-e3;
    float zm = fmaxf(fmaxf(z0,z1), fmaxf(z2,z3));
    float p0=__expf(z0-zm), p1=__expf(z1-zm), p2=__expf(z2-zm), p3=__expf(z3-zm);
    float inv = 1.f/(p0+p1+p2+p3);
    pw[tid][0]=p0*inv; pw[tid][1]=p1*inv; pw[tid][2]=p2*inv; pw[tid][3]=p3*inv;
  }
  __syncthreads();
  int n0 = blockIdx.x*256;
  int n = n0 + tid;
  float yv[4];
  #pragma unroll
  for (int k = 0; k < 4; ++k){
    float m  = sums[k]*invc;
    float vv = fmaxf(sums[4+k]*invc - m*m, 0.f);
    float sck = ce_g[k]*rsqrtf(vv + 1e-5f);
    float bbk = ce_b[k] - m*sck;
    yv[k] = fmaxf(fmaf(yc[((size_t)b*4+k)*Nn + n], sck, bbk), 0.f);
  }
  float sc = scp[0];
  const float* xb = x + (size_t)b*64*Nn + n;
  float a[64];
  #pragma unroll
  for (int c = 0; c < 64; ++c){
    a[c] = fmaf(sc, pw[c][0]*yv[0] + pw[c][1]*yv[1] + pw[c][2]*yv[2] + pw[c][3]*yv[3],
                xb[(size_t)c*Nn]);
  }
  unsigned vals[32];
  pack_pairs(a, vals);
  staged_write(lds, tid, vals, (uint4*)PG4, (size_t)((2+which)*4 + b)*Nn + n0, 8, 0, nullptr);
}

// ---------------- TAM ----------------

__launch_bounds__(256)
__global__ void k_tamenergy_mf(const unsigned short* __restrict__ X,
                               const unsigned short* __restrict__ Y,
                               float* __restrict__ E){
  int b = blockIdx.z;
  int wave = threadIdx.x >> 6, lane = threadIdx.x & 63;
  int r = lane & 15, g = lane >> 4;
  const unsigned short* Xb = X + (size_t)b*32*82944;
  const unsigned short* Yb = Y + (size_t)b*32*82944;
  f32x4 a00 = (f32x4){0.f,0.f,0.f,0.f};
  f32x4 a01 = a00, a10 = a00, a11 = a00;
  int c0 = (blockIdx.x*4 + wave)*8;
  for (int cc = 0; cc < 8; ++cc){
    size_t k0 = (size_t)(c0 + cc)*32 + (size_t)g*8;
    bf16x8 x0 = *(const bf16x8*)(Xb + (size_t)r*82944 + k0);
    bf16x8 x1 = *(const bf16x8*)(Xb + (size_t)(r+16)*82944 + k0);
    bf16x8 y0 = *(const bf16x8*)(Yb + (size_t)r*82944 + k0);
    bf16x8 y1 = *(const bf16x8*)(Yb + (size_t)(r+16)*82944 + k0);
    a00 = __builtin_amdgcn_mfma_f32_16x16x32_bf16(x0, y0, a00, 0, 0, 0);
    a01 = __builtin_amdgcn_mfma_f32_16x16x32_bf16(x0, y1, a01, 0, 0, 0);
    a10 = __builtin_amdgcn_mfma_f32_16x16x32_bf16(x1, y0, a10, 0, 0, 0);
    a11 = __builtin_amdgcn_mfma_f32_16x16x32_bf16(x1, y1, a11, 0, 0, 0);
  }
  float* Eb = E + (size_t)b*1024;
  #pragma unroll
  for (int rr = 0; rr < 4; ++rr){
    int row = g*4 + rr;
    atomicAdd(&Eb[row*32 + r],           a00[rr]);
    atomicAdd(&Eb[row*32 + 16 + r],      a01[rr]);
    atomicAdd(&Eb[(row+16)*32 + r],      a10[rr]);
    atomicAdd(&Eb[(row+16)*32 + 16 + r], a11[rr]);
  }
}

__launch_bounds__(256)
__global__ void k_tamapply_mf(const unsigned short* __restrict__ Xbf,
                              const unsigned short* __restrict__ Ybf,
                              const float* __restrict__ e, const float* __restrict__ scp,
                              unsigned short* __restrict__ Pout){
  __shared__ unsigned short yl[32*8*TAPAD];
  __shared__ float al[1024];
  int b = blockIdx.z, tid = threadIdx.x;
  int hw0 = blockIdx.x*8;
  if (tid < 32){
    const float* er = e + (size_t)b*1024 + tid*32;
    float mx = -1e30f, mn = 1e30f;
    for (int j = 0; j < 32; ++j){ mx = fmaxf(mx, er[j]); mn = fminf(mn, er[j]); }
    float zmax = mx - mn;
    float sum = 0.f;
    for (int j = 0; j < 32; ++j){
      float p = __expf((mx - er[j]) - zmax);
      al[tid*32 + j] = p; sum += p;
    }
    float inv = 1.f/sum;
    for (int j = 0; j < 32; ++j) al[tid*32 + j] *= inv;
  }
  const uint4* src = (const uint4*)Ybf + (size_t)b*N2*8;
  #pragma unroll
  for (int it = 0; it < 8; ++it){
    int idx = it*256 + tid;
    int j = idx >> 6, rem = idx & 63, h = rem >> 3, w = rem & 7;
    uint4 v = src[(size_t)(j*1296 + hw0 + h)*8 + w];
    *(uint4*)&yl[(j*8+h)*TAPAD + w*8] = v;
  }
  __syncthreads();
  int t = tid >> 3, h = tid & 7;
  int n = t*1296 + hw0 + h;
  float sc = scp[0];
  const uint4* xr = (const uint4*)Xbf + ((size_t)b*N2 + n)*8;
  float acc[64];
  #pragma unroll
  for (int w = 0; w < 8; ++w){
    uint4 v = xr[w];
    acc[w*8+0] = b2f_lo(v.x); acc[w*8+1] = b2f_hi(v.x);
    acc[w*8+2] = b2f_lo(v.y); acc[w*8+3] = b2f_hi(v.y);
    acc[w*8+4] = b2f_lo(v.z); acc[w*8+5] = b2f_hi(v.z);
    acc[w*8+6] = b2f_lo(v.w); acc[w*8+7] = b2f_hi(v.w);
  }
  const float* ar = &al[t*32];
  for (int j = 0; j < 32; ++j){
    float aj = sc * ar[j];
    const uint4* yr = (const uint4*)&yl[(j*8+h)*TAPAD];
    #pragma unroll
    for (int w = 0; w < 8; ++w){
      uint4 v = yr[w];
      acc[w*8+0] = fmaf(aj, b2f_lo(v.x), acc[w*8+0]);
      acc[w*8+1] = fmaf(aj, b2f_hi(v.x), acc[w*8+1]);
      acc[w*8+2] = fmaf(aj, b2f_lo(v.y), acc[w*8+2]);
      acc[w*8+3] = fmaf(aj, b2f_hi(v.y), acc[w*8+3]);
      acc[w*8+4] = fmaf(aj, b2f_lo(v.z), acc[w*8+4]);
      acc[w*8+5] = fmaf(aj, b2f_hi(v.z), acc[w*8+5]);
      acc[w*8+6] = fmaf(aj, b2f_lo(v.w), acc[w*8+6]);
      acc[w*8+7] = fmaf(aj, b2f_hi(v.w), acc[w*8+7]);
    }
  }
  uint4* orow = (uint4*)Pout + ((size_t)b*N2 + n)*8;
  #pragma unroll
  for (int w = 0; w < 8; ++w){
    uint4 v;
    v.x = (unsigned)f2b(acc[w*8+0]) | ((unsigned)f2b(acc[w*8+1]) << 16);
    v.y = (unsigned)f2b(acc[w*8+2]) | ((unsigned)f2b(acc[w*8+3]) << 16);
    v.z = (unsigned)f2b(acc[w*8+4]) | ((unsigned)f2b(acc[w*8+5]) << 16);
    v.w = (unsigned)f2b(acc[w*8+6]) | ((unsigned)f2b(acc[w*8+7]) << 16);
    orow[w] = v;
  }
}

// ---------------- host ----------------

extern "C" void kernel_launch(void* const* d_in, const int* in_sizes, int n_in,
                              void* d_out, int out_size, void* d_ws, size_t ws_size,
                              hipStream_t stream) {
  const float* x1      = (const float*)d_in[0];
  const float* x2      = (const float*)d_in[1];
  const float* w_conv1 = (const float*)d_in[2];
  const float* g_conv1 = (const float*)d_in[3];
  const float* b_conv1 = (const float*)d_in[4];
  const float* w_conv2 = (const float*)d_in[5];
  const float* g_conv2 = (const float*)d_in[6];
  const float* b_conv2 = (const float*)d_in[7];
  const float* w_tam   = (const float*)d_in[8];
  const float* g_tam   = (const float*)d_in[9];
  const float* b_tam   = (const float*)d_in[10];
  const float* w_cat   = (const float*)d_in[11];
  const float* g_cat   = (const float*)d_in[12];
  const float* b_cat   = (const float*)d_in[13];
  const float* pe_w    = (const float*)d_in[14];
  const float* pe_g    = (const float*)d_in[15];
  const float* pe_b    = (const float*)d_in[16];
  const float* pd_wq   = (const float*)d_in[17];
  const float* pd_bq   = (const float*)d_in[18];
  const float* pd_wk   = (const float*)d_in[19];
  const float* pd_bk   = (const float*)d_in[20];
  const float* pd_wv   = (const float*)d_in[21];
  const float* pd_bv   = (const float*)d_in[22];
  const float* pd_scale= (const float*)d_in[23];
  const float* ce_w    = (const float*)d_in[24];
  const float* ce_g    = (const float*)d_in[25];
  const float* ce_b    = (const float*)d_in[26];
  const float* cd_scale= (const float*)d_in[27];
  const float* te_w    = (const float*)d_in[28];
  const float* te_g    = (const float*)d_in[29];
  const float* te_b    = (const float*)d_in[30];
  const float* td_scale= (const float*)d_in[31];

  float* ws = (float*)d_ws;
  size_t off = 0;
  auto alloc = [&](size_t n){ float* p = ws + off; off += (n + 3) & ~(size_t)3; return p; };
  float* stats = alloc(16384);   // 32 slots x 512   [zeroed]
  float* e_tam = alloc(4096);    //                  [zeroed]
  float* e_cam = alloc(2048);    //                  [zeroed]
  float* p6a   = alloc(9216);    //                  [zeroed]
  float* p6b   = alloc(9216);    //                  [zeroed]
  float* wTce  = alloc(256);
  unsigned short* Wp1  = (unsigned short*)alloc(24576);
  unsigned short* Wp2  = (unsigned short*)alloc(6144);
  unsigned short* Wpt  = (unsigned short*)alloc(6144);
  unsigned short* Wpc  = (unsigned short*)alloc(73728);
  unsigned short* Wpte = (unsigned short*)alloc(2048);
  float* pf2   = alloc(25600);
  float* vb2   = alloc(25600);
  float* KW2   = alloc(25600);
  float* sb2   = alloc(512);
  float* yc2   = alloc(663552);
  float* Mb    = alloc(663552);
  float* A     = alloc(5308416);
  float* Bb    = alloc(5308416);   // contiguous after A
  float* PTEf  = alloc(5308416);
  float* COMB  = alloc(31850496);

  unsigned short* P0 = (unsigned short*)COMB;
  unsigned short* DdBF = (unsigned short*)COMB;                 // te raw bf16
  unsigned short* Dbf  = (unsigned short*)(COMB + 10616832);    // BN'd xt2 bf16
  unsigned short* PTAM = (unsigned short*)(COMB + 15925248);
  unsigned short* RrawBF = (unsigned short*)COMB;               // tam conv raw bf16
  unsigned short* PCAT1 = (unsigned short*)(COMB + 5308416);
  unsigned short* PCAT2 = (unsigned short*)(COMB + 13271040);
  unsigned short* PG4   = (unsigned short*)(COMB + 21233664);   // [4][4][Nn][64] bf16
  unsigned short* R4    = (unsigned short*)A;                   // conv2 raw bf16 (A+Bb dead)
  unsigned short* CATR1 = (unsigned short*)(COMB + 21233664);   // over dead PG4
  unsigned short* CATR2 = (unsigned short*)A;                   // over dead R4
  unsigned short* PTE = (unsigned short*)PTEf;

  const float invc16 = 1.f/(4.f*20736.f);
  const float invc32 = 1.f/(4.f*41472.f);

  // zero stats + e_tam + e_cam + p6a + p6b (contiguous 40960 floats)
  k_zero<<<dim3(160), 256, 0, stream>>>(stats, 40960);
  k_wprep<<<dim3(881), 256, 0, stream>>>(w_conv1, w_conv2, w_tam, w_cat, te_w, ce_w,
                                         Wp1, Wp2, Wpt, Wpc, Wpte, wTce);
  k_convT<<<dim3(81, 1, 8), 256, 0, stream>>>(x1, x2, P0);

  // conv1 A & B merged; boundary planes Mb
  k_mfconv_ab<<<dim3(7,16,8), 256, 0, stream>>>(P0, Wp1, A, Bb, stats);
  k_mfconv<<<dim3(7,2,4), 256, 0, stream>>>(P0, Wp1, Mb, 256, 64, 1, 2, 1, 3, 1, 15, 0, 32, 32, stats + 21*512, 0);
  k_planestats<<<dim3(1,64,2), 256, 0, stream>>>(A, Bb, stats + 22*512, stats + 23*512);
  k_combine<<<dim3(1), 128, 0, stream>>>(stats);
  k_bnT_cc<<<dim3(162,1,4), 256, 0, stream>>>(A, Mb, Bb, stats + 2*512,
                                              g_conv1, b_conv1, invc32, PTE);

  // xt2 = pw_bn_relu(xt1, te_w)
  k_mfconv<<<dim3(7,32,4), 256, 0, stream>>>(PTE, Wpte, (float*)DdBF, 64, 64, 1, 32, 1, 1, 0, 0, 0, 32, 32, stats + 3*512, 1);
  k_bnT<<<dim3(162,1,4), 256, 0, stream>>>(DdBF, stats + 3*512, te_g, te_b, invc32,
                                           Dbf, nullptr, N2, 64, 0, 1);

  // TAM
  k_tamenergy_mf<<<dim3(81, 1, 4), 256, 0, stream>>>(PTE, Dbf, e_tam);
  k_tamapply_mf<<<dim3(162, 1, 4), 256, 0, stream>>>(PTE, Dbf, e_tam, td_scale, PTAM);
  k_mfconv<<<dim3(7,16,4), 256, 0, stream>>>(PTAM, Wpt, (float*)RrawBF, 64, 64, 1, 16, 2, 3, 1, 0, 0, 32, 32, stats + 4*512, 1);
  k_bnT<<<dim3(81,1,4), 256, 0, stream>>>(RrawBF, stats + 4*512, g_tam, b_tam, invc16,
                                          PCAT1, PCAT2, Nn, 192, 128, 1);

  // both branches merged (z=8)
  k_bnrelu_mean2<<<dim3(6,64,8), 256, 0, stream>>>(A, Bb, stats, g_conv1, b_conv1,
                                                   invc16, p6a, p6b);
  k_pamenc1m<<<dim3(50,1,8), 64, 0, stream>>>(p6a, p6b, pe_w, pf2, stats);
  k_pamenc2m<<<dim3(50,1,8), 128, 0, stream>>>(pf2, stats, pe_g, pe_b,
                                               pd_wk, pd_bk, pd_wv, pd_bv, pd_wq, pd_bq,
                                               vb2, KW2, sb2);
  k_pamattnm<<<dim3(81,1,8), 256, 0, stream>>>(A, Bb, KW2, sb2, vb2, pd_scale, PG4);
  k_tconvm<<<dim3(6,16,8), dim3(4,64), 0, stream>>>(A, Bb, wTce, yc2, stats);
  k_camenergy2m<<<dim3(81,1,8), 256, 0, stream>>>(A, Bb, yc2, stats, ce_g, ce_b,
                                                  invc16, e_cam);
  k_camapplyTm<<<dim3(81,1,8), 256, 0, stream>>>(A, Bb, yc2, stats, ce_g, ce_b,
                                                 invc16, e_cam, cd_scale, PG4);

  // all four conv2's in one launch (A/Bb now dead -> R4 reuses them)
  k_mfconv4<<<dim3(7,16,16), 256, 0, stream>>>(PG4, Wp2, R4, stats);
  k_bnT4<<<dim3(81,1,16), 256, 0, stream>>>(R4, stats, g_conv2, b_conv2, invc16,
                                            PCAT1, PCAT2);

  // both cat convs in one launch (round-12 proven block-per-chunk) -> BN out
  k_mfconvcat<<<dim3(7,16,32), 256, 0, stream>>>(PCAT1, PCAT2, Wpc, CATR1, CATR2, stats);
  k_bnrelu_out<<<dim3(11, 256, 8), 256, 0, stream>>>(CATR1, CATR2, stats + 19*512,
                                                     g_cat, b_cat, invc16, (float*)d_out);
}